// Round 12
// baseline (251.360 us; speedup 1.0000x reference)
//
#include <hip/hip_runtime.h>
#include <cmath>

typedef __bf16 bf16x8 __attribute__((ext_vector_type(8)));
typedef __bf16 bf16x4 __attribute__((ext_vector_type(4)));
typedef float  f32x4  __attribute__((ext_vector_type(4)));
typedef float  f32x2  __attribute__((ext_vector_type(2)));

#define B_  8
#define L_  1024
#define DM  256
#define DI  512
#define DS  16
#define DTR 16
#define M_  (B_*L_)
#define NC  32
#define CT  32

__device__ inline float softplus_f(float z){
  return (z > 20.f) ? z : __logf(1.f + __expf(z));
}
__device__ inline float silu_f(float z){
  return z / (1.f + __expf(-z));
}

// ---- inline dtype detector ----
__device__ inline int flag_from_x(const void* x){
  const unsigned short* u = (const unsigned short*)x;
  int lane = threadIdx.x & 63;
  unsigned short v = u[2*lane];
  int e = (v >> 7) & 0xFF;
  unsigned long long m = __ballot(e >= 160 || e < 96);
  return __popcll(m) > 16;   // 1 = inputs are fp32
}

// ---------------- unified weight prep: tiled transposes + elementwise ----------------
struct PrepJob { const void* src; void* dst; int rows; int cols; int f32out; };
struct PrepArgs { PrepJob j[26]; int nj; };
struct TJob { const void* src; __bf16* dst; int R; int C; };
struct TArgs { TJob j[3]; int ntiles[3]; int nj; int ntot; };

__global__ __launch_bounds__(256) void wprep_k(TArgs ta, PrepArgs a, const void* xsrc){
  const int f = flag_from_x(xsrc);
  const int tid = threadIdx.x;
  if ((int)blockIdx.x < ta.ntot){
    __shared__ float tile[64][65];
    int bid = blockIdx.x;
    int jj = 0;
    while (jj < ta.nj-1 && bid >= ta.ntiles[jj]) { bid -= ta.ntiles[jj]; jj++; }
    const TJob J = ta.j[jj];
    const int tpr = J.C >> 6;
    const int tr = bid / tpr, tc = bid - tr*tpr;
    const int r0 = tr*64, c0 = tc*64;
    #pragma unroll
    for (int i=0;i<16;i++){
      int idx = i*256 + tid;
      int r = idx >> 6, c = idx & 63;
      long off = (long)(r0+r)*J.C + c0 + c;
      tile[r][c] = f ? ((const float*)J.src)[off] : (float)((const __bf16*)J.src)[off];
    }
    __syncthreads();
    #pragma unroll
    for (int i=0;i<16;i++){
      int idx = i*256 + tid;
      int c = idx >> 6, r = idx & 63;
      J.dst[(long)(c0+c)*J.R + r0 + r] = (__bf16)tile[r][c];
    }
  } else {
    int e = (blockIdx.x - ta.ntot)*256 + tid;
    #pragma unroll 1
    for (int jj=0; jj<a.nj; jj++){
      int sz = a.j[jj].rows * a.j[jj].cols;
      if (e < sz){
        int cols = a.j[jj].cols;
        int r = e / cols, c = e - r*cols;
        float v = f ? ((const float*)a.j[jj].src)[e] : (float)((const __bf16*)a.j[jj].src)[e];
        if (a.j[jj].f32out) ((float*)a.j[jj].dst)[c*a.j[jj].rows + r] = v;
        else ((__bf16*)a.j[jj].dst)[(long)c*a.j[jj].rows + r] = (__bf16)v;
        return;
      }
      e -= sz;
    }
  }
}

// ---------------- LayerNorm + wcomb tail blocks ----------------
__global__ __launch_bounds__(256) void lnw_k(
    const void* x, const __bf16* g, const __bf16* bb, __bf16* xn,
    const __bf16* fusWt, const __bf16* outWr0, const __bf16* outWr1,
    __bf16* BtC0, __bf16* BtC1)
{
  const int bx = blockIdx.x;
  const int tid = threadIdx.x;
  const int lane = tid & 63;
  const int wid = tid >> 6;

  if (bx < M_/4){
    const int f = flag_from_x(x);
    long row = (long)bx*4 + wid;
    long base = row*DM + lane*4;
    float v0,v1,v2,v3;
    if (f){ f32x4 xv = *(const f32x4*)((const float*)x + base);
            v0=xv[0]; v1=xv[1]; v2=xv[2]; v3=xv[3]; }
    else  { bf16x4 xv = *(const bf16x4*)((const __bf16*)x + base);
            v0=(float)xv[0]; v1=(float)xv[1]; v2=(float)xv[2]; v3=(float)xv[3]; }
    float s = v0+v1+v2+v3;
    float q = v0*v0+v1*v1+v2*v2+v3*v3;
    #pragma unroll
    for (int off=32; off>0; off>>=1){ s += __shfl_xor(s,off); q += __shfl_xor(q,off); }
    float mu = s*(1.f/DM), var = q*(1.f/DM)-mu*mu;
    float rs = rsqrtf(var+1e-5f);
    bf16x4 gv = *(const bf16x4*)(g + lane*4);
    bf16x4 bv = *(const bf16x4*)(bb + lane*4);
    bf16x4 o;
    o[0]=(__bf16)((v0-mu)*rs*(float)gv[0]+(float)bv[0]);
    o[1]=(__bf16)((v1-mu)*rs*(float)gv[1]+(float)bv[1]);
    o[2]=(__bf16)((v2-mu)*rs*(float)gv[2]+(float)bv[2]);
    o[3]=(__bf16)((v3-mu)*rs*(float)gv[3]+(float)bv[3]);
    *(bf16x4*)(xn + base) = o;
  } else {
    int b2 = bx - M_/4;
    int wz  = b2 >> 5;
    int rem = b2 & 31;
    int gx = rem & 3, gy = rem >> 2;
    const __bf16* A  = fusWt + wz*DM;
    const __bf16* Bt = wz ? outWr1 : outWr0;
    __bf16* C = wz ? BtC1 : BtC0;
    const int mBase = (gx*4 + wid)*16;
    const int nBase = gy*64;
    const int lm = lane & 15;
    const int kq = (lane >> 4)*8;
    long aoff = (long)(mBase+lm)*(2*DM) + kq;
    long boff[4];
    #pragma unroll
    for (int j=0;j<4;j++) boff[j] = (long)(nBase+j*16+lm)*DM + kq;
    f32x4 acc[4] = {};
    #pragma unroll
    for (int k0=0;k0<DM;k0+=32){
      bf16x8 af = *(const bf16x8*)(A + aoff + k0);
      bf16x8 bfr[4];
      #pragma unroll
      for (int j=0;j<4;j++) bfr[j] = *(const bf16x8*)(Bt + boff[j] + k0);
      #pragma unroll
      for (int j=0;j<4;j++)
        acc[j] = __builtin_amdgcn_mfma_f32_16x16x32_bf16(af, bfr[j], acc[j], 0,0,0);
    }
    #pragma unroll
    for (int rr=0;rr<4;rr++){
      int r = mBase + (lane>>4)*4 + rr;
      #pragma unroll
      for (int j=0;j<4;j++){
        int c = nBase + j*16 + lm;
        C[(long)r*DI + c] = (__bf16)acc[j][rr];
      }
    }
  }
}

// ============ LDS-staged MFMA GEMM (in-proj) ============
template<int BM,int BN,int KK>
__global__ __launch_bounds__(256) void gemm_in_k(
    const __bf16* A, const __bf16* B0, const __bf16* B1,
    __bf16* xz0, __bf16* xz1, __bf16* res0, __bf16* res1,
    int lda, int ldb)
{
  constexpr int TM = BM/2, TN = BN/2;
  constexpr int WMT = TM/16, WNT = TN/16;
  constexpr int LA = BM/64, LB = BN/64;

  const int dir = blockIdx.z;
  const __bf16* Bt = dir ? B1 : B0;
  __bf16* xz  = dir ? xz1 : xz0;
  __bf16* res = dir ? res1 : res0;
  const int tid  = threadIdx.x;
  const int lane = tid & 63;
  const int wid  = tid >> 6;
  const int wm = wid & 1;
  const int wn = wid >> 1;
  const int mBase = blockIdx.x * BM;
  const int nBase = blockIdx.y * BN;
  const int lm = lane & 15;
  const int kq = (lane >> 4) * 8;

  __shared__ __bf16 As[BM*32];
  __shared__ __bf16 Bs[BN*32];

  const __bf16* aS[LA];
  const __bf16* bS[LB];
  {
    int colk = (tid & 3) * 8;
    #pragma unroll
    for (int ld=0; ld<LA; ld++){
      int r = mBase + ld*64 + (tid >> 2);
      if (dir==1){ int b = r >> 10, t = r & (L_-1); r = (b<<10) + (L_-1-t); }
      aS[ld] = A + (long)r*lda + colk;
    }
    #pragma unroll
    for (int ld=0; ld<LB; ld++){
      int r = nBase + ld*64 + (tid >> 2);
      bS[ld] = Bt + (long)r*ldb + colk;
    }
  }

  f32x4 acc[WMT][WNT] = {};
  for (int k0=0; k0<KK; k0+=32){
    #pragma unroll
    for (int ld=0; ld<LA; ld++)
      __builtin_amdgcn_global_load_lds(
        (const __attribute__((address_space(1))) void*)(aS[ld] + k0),
        (__attribute__((address_space(3))) void*)(&As[ld*2048 + tid*8]), 16, 0, 0);
    #pragma unroll
    for (int ld=0; ld<LB; ld++)
      __builtin_amdgcn_global_load_lds(
        (const __attribute__((address_space(1))) void*)(bS[ld] + k0),
        (__attribute__((address_space(3))) void*)(&Bs[ld*2048 + tid*8]), 16, 0, 0);
    __syncthreads();
    bf16x8 af[WMT], bfr[WNT];
    #pragma unroll
    for (int i=0;i<WMT;i++) af[i]  = *(const bf16x8*)&As[(wm*TM + i*16 + lm)*32 + kq];
    #pragma unroll
    for (int j=0;j<WNT;j++) bfr[j] = *(const bf16x8*)&Bs[(wn*TN + j*16 + lm)*32 + kq];
    #pragma unroll
    for (int i=0;i<WMT;i++)
      #pragma unroll
      for (int j=0;j<WNT;j++)
        acc[i][j] = __builtin_amdgcn_mfma_f32_16x16x32_bf16(af[i], bfr[j], acc[i][j], 0,0,0);
    __syncthreads();
  }

  #pragma unroll
  for (int i=0;i<WMT;i++){
    #pragma unroll
    for (int rr=0;rr<4;rr++){
      int r = mBase + wm*TM + i*16 + (lane>>4)*4 + rr;
      #pragma unroll
      for (int j=0;j<WNT;j++){
        int c = nBase + wn*TN + j*16 + lm;
        float v = acc[i][j][rr];
        if (c < DI) xz[(long)r*DI + c] = (__bf16)v;
        else        res[(long)r*DI + (c-DI)] = (__bf16)v;
      }
    }
  }
}

// ============ final fused GEMM ============
template<int BM,int BN,int KK>
__global__ __launch_bounds__(256) void gemm_fin_k(
    const __bf16* Af, const __bf16* Ab,
    const __bf16* Bt0, const __bf16* Bt1,
    void* Cout, const __bf16* bias, const void* resid)
{
  constexpr int TM = BM/2, TN = BN/2;
  constexpr int WMT = TM/16, WNT = TN/16;
  constexpr int LA = BM/64, LB = BN/64;

  const int of = flag_from_x(resid);
  const int tid  = threadIdx.x;
  const int lane = tid & 63;
  const int wid  = tid >> 6;
  const int wm = wid & 1;
  const int wn = wid >> 1;
  const int mBase = blockIdx.x * BM;
  const int nBase = blockIdx.y * BN;
  const int lm = lane & 15;
  const int kq = (lane >> 4) * 8;

  __shared__ __bf16 As[BM*32];
  __shared__ __bf16 Bs[BN*32];

  f32x4 acc[WMT][WNT] = {};
  #pragma unroll 1
  for (int dd=0; dd<2; dd++){
    const __bf16* A  = dd ? Ab  : Af;
    const __bf16* Bt = dd ? Bt1 : Bt0;
    const __bf16* aS[LA];
    const __bf16* bS[LB];
    {
      int colk = (tid & 3) * 8;
      #pragma unroll
      for (int ld=0; ld<LA; ld++){
        int r = mBase + ld*64 + (tid >> 2);
        if (dd==1){ int b = r >> 10, t = r & (L_-1); r = (b<<10) + (L_-1-t); }
        aS[ld] = A + (long)r*DI + colk;
      }
      #pragma unroll
      for (int ld=0; ld<LB; ld++){
        int r = nBase + ld*64 + (tid >> 2);
        bS[ld] = Bt + (long)r*DI + colk;
      }
    }
    for (int k0=0; k0<KK; k0+=32){
      #pragma unroll
      for (int ld=0; ld<LA; ld++)
        __builtin_amdgcn_global_load_lds(
          (const __attribute__((address_space(1))) void*)(aS[ld] + k0),
          (__attribute__((address_space(3))) void*)(&As[ld*2048 + tid*8]), 16, 0, 0);
      #pragma unroll
      for (int ld=0; ld<LB; ld++)
        __builtin_amdgcn_global_load_lds(
          (const __attribute__((address_space(1))) void*)(bS[ld] + k0),
          (__attribute__((address_space(3))) void*)(&Bs[ld*2048 + tid*8]), 16, 0, 0);
      __syncthreads();
      bf16x8 af[WMT], bfr[WNT];
      #pragma unroll
      for (int i=0;i<WMT;i++) af[i]  = *(const bf16x8*)&As[(wm*TM + i*16 + lm)*32 + kq];
      #pragma unroll
      for (int j=0;j<WNT;j++) bfr[j] = *(const bf16x8*)&Bs[(wn*TN + j*16 + lm)*32 + kq];
      #pragma unroll
      for (int i=0;i<WMT;i++)
        #pragma unroll
        for (int j=0;j<WNT;j++)
          acc[i][j] = __builtin_amdgcn_mfma_f32_16x16x32_bf16(af[i], bfr[j], acc[i][j], 0,0,0);
      __syncthreads();
    }
  }

  #pragma unroll
  for (int i=0;i<WMT;i++){
    #pragma unroll
    for (int rr=0;rr<4;rr++){
      int r = mBase + wm*TM + i*16 + (lane>>4)*4 + rr;
      #pragma unroll
      for (int j=0;j<WNT;j++){
        int c = nBase + wn*TN + j*16 + lm;
        float v = acc[i][j][rr];
        float rsd = of ? ((const float*)resid)[(long)r*DM + c]
                       : (float)((const __bf16*)resid)[(long)r*DM + c];
        v += (float)bias[c] + rsd;
        if (of) ((float*)Cout)[(long)r*DM + c] = v;
        else    ((__bf16*)Cout)[(long)r*DM + c] = (__bf16)v;
      }
    }
  }
}

// ============ scan phase A: conv + x-proj MFMA + local scan, with xs/sX write-through ============
__global__ __launch_bounds__(512) void scanA_k(
    const __bf16* xz0, const __bf16* xz1,
    const float* cw0, const float* cw1,
    const __bf16* cb0, const __bf16* cb1,
    const __bf16* xW0, const __bf16* xW1,
    const float* dw0, const float* dw1,
    const __bf16* dtB0, const __bf16* dtB1,
    const float* ALf0, const float* ALf1,
    __bf16* xg0, __bf16* xg1,
    float* sg0, float* sg1,
    float* hend, float* sumd)
{
  const int dir = blockIdx.z;
  const __bf16* xz  = dir ? xz1 : xz0;
  const float*  cw  = dir ? cw1 : cw0;
  const __bf16* cb  = dir ? cb1 : cb0;
  const __bf16* xWt = dir ? xW1 : xW0;
  const float*  dw  = dir ? dw1 : dw0;
  const __bf16* dtB = dir ? dtB1 : dtB0;
  const float*  ALf = dir ? ALf1 : ALf0;
  __bf16*       xg  = dir ? xg1 : xg0;
  float*        sg  = dir ? sg1 : sg0;

  const int b   = blockIdx.y;
  const int c   = blockIdx.x;
  const int tid = threadIdx.x;
  const int lane = tid & 63;
  const int wid  = tid >> 6;
  const int d   = tid;
  const int db  = dir*8 + b;
  const long row0 = (long)b*L_ + (long)c*CT;

  __shared__ __bf16 xs_s[CT*DI];    // 32KB, XOR-swizzled, row stride 1024B
  __shared__ float  sX[CT][48];     // dlt | B | C

  // ---- conv + silu -> xs LDS + global write-through (load-all-first) ----
  {
    const float q0 = cw[0*DI+d], q1 = cw[1*DI+d], q2 = cw[2*DI+d], q3 = cw[3*DI+d];
    const float cbv = (float)cb[d];
    int gt0 = c*CT;
    float xt[CT];
    #pragma unroll
    for (int t=0;t<CT;t++) xt[t] = (float)xz[(row0+t)*DI + d];
    float xm3 = (gt0-3 >= 0) ? (float)xz[(row0-3)*DI + d] : 0.f;
    float xm2 = (gt0-2 >= 0) ? (float)xz[(row0-2)*DI + d] : 0.f;
    float xm1 = (gt0-1 >= 0) ? (float)xz[(row0-1)*DI + d] : 0.f;
    #pragma unroll
    for (int t=0;t<CT;t++){
      float av = cbv;
      av += xm3*q0; av += xm2*q1; av += xm1*q2; av += xt[t]*q3;
      __bf16 sv = (__bf16)silu_f(av);
      *(__bf16*)((char*)xs_s + t*1024 + ((2*d) ^ ((t&7)<<4))) = sv;
      xg[(row0+t)*DI + d] = sv;
      xm3 = xm2; xm2 = xm1; xm1 = xt[t];
    }
  }
  __syncthreads();

  // ---- x-proj: sX[32][48] = xs[32][512] @ xW^T  (6 waves) + global write-through ----
  if (wid < 6){
    const int mb = (wid & 1) * 16;
    const int nb = (wid >> 1) * 16;
    const int lm = lane & 15;
    const int kq = (lane >> 4) * 8;
    const int row = mb + lm;
    const char* abase = (const char*)xs_s + row*1024;
    const int rsw = (row&7)<<4;
    const __bf16* Bt = xWt + (long)(nb + lm)*DI + kq;
    f32x4 acc = {};
    #pragma unroll
    for (int k0=0;k0<DI;k0+=32){
      bf16x8 af  = *(const bf16x8*)(abase + (((kq + k0)*2) ^ rsw));
      bf16x8 bfr = *(const bf16x8*)(Bt + k0);
      acc = __builtin_amdgcn_mfma_f32_16x16x32_bf16(af, bfr, acc, 0,0,0);
    }
    #pragma unroll
    for (int rr=0;rr<4;rr++){
      int r = mb + (lane>>4)*4 + rr;
      sX[r][nb + lm] = acc[rr];
      sg[(row0 + r)*48 + nb + lm] = acc[rr];
    }
  }

  // ---- per-thread scan state ----
  f32x2 dw2[8];
  { const f32x4* p = (const f32x4*)(dw + d*DTR);
    #pragma unroll
    for (int q=0;q<4;q++){ f32x4 v=p[q];
      dw2[q*2]   = f32x2{v[0],v[1]};
      dw2[q*2+1] = f32x2{v[2],v[3]}; } }
  float A[16];
  { const f32x4* p = (const f32x4*)(ALf + d*DS);
    #pragma unroll
    for (int q=0;q<4;q++){ f32x4 v=p[q];
      A[q*4]=-__expf(v[0]); A[q*4+1]=-__expf(v[1]); A[q*4+2]=-__expf(v[2]); A[q*4+3]=-__expf(v[3]); } }
  bool pow_ok = true;
  #pragma unroll
  for (int n=0;n<16;n++) pow_ok = pow_ok && (fabsf(A[n] + (float)(n+1)) < 0.003f*(n+1));
  const float dtbv = (float)dtB[d];

  f32x2 h2[8];
  #pragma unroll
  for (int i=0;i<8;i++) h2[i] = f32x2{0.f,0.f};
  float sdelta = 0.f;
  __syncthreads();

  if (pow_ok){
    #pragma unroll 2
    for (int t=0;t<CT;t++){
      f32x2 z2 = f32x2{dtbv, 0.f};
      #pragma unroll
      for (int i=0;i<8;i++){
        f32x2 qv = *(const f32x2*)&sX[t][i*2];
        z2 += qv*dw2[i];
      }
      float delta = softplus_f(z2[0]+z2[1]);
      sdelta += delta;
      float xv = (float)*(const __bf16*)((const char*)xs_s + t*1024 + ((2*d) ^ ((t&7)<<4)));
      float dx = delta*xv;
      f32x2 dx2 = f32x2{dx, dx};
      float e1 = __expf(-delta), e2v = e1*e1;
      f32x2 e22 = f32x2{e2v, e2v};
      f32x2 pw = f32x2{e1, e2v};
      #pragma unroll
      for (int i=0;i<8;i++){
        f32x2 Bv = *(const f32x2*)&sX[t][16+i*2];
        h2[i] = pw*h2[i] + dx2*Bv;
        pw = pw*e22;
      }
    }
  } else {
    #pragma unroll 2
    for (int t=0;t<CT;t++){
      f32x2 z2 = f32x2{dtbv, 0.f};
      #pragma unroll
      for (int i=0;i<8;i++){
        f32x2 qv = *(const f32x2*)&sX[t][i*2];
        z2 += qv*dw2[i];
      }
      float delta = softplus_f(z2[0]+z2[1]);
      sdelta += delta;
      float xv = (float)*(const __bf16*)((const char*)xs_s + t*1024 + ((2*d) ^ ((t&7)<<4)));
      float dx = delta*xv;
      #pragma unroll
      for (int i=0;i<8;i++){
        f32x2 Bv = *(const f32x2*)&sX[t][16+i*2];
        f32x2 pw = f32x2{__expf(delta*A[i*2]), __expf(delta*A[i*2+1])};
        h2[i] = pw*h2[i] + f32x2{dx,dx}*Bv;
      }
    }
  }

  long hb = (((long)db*NC + c)*DI + d)*16;
  f32x4* hp = (f32x4*)(hend + hb);
  #pragma unroll
  for (int q=0;q<4;q++){
    f32x4 v; v[0]=h2[q*2][0]; v[1]=h2[q*2][1]; v[2]=h2[q*2+1][0]; v[3]=h2[q*2+1][1];
    hp[q]=v;
  }
  sumd[((long)db*NC + c)*DI + d] = sdelta;
}

// ============ phase B: cross-chunk scan, register-prefetched ============
__global__ __launch_bounds__(256) void scanB_k(
    const float* ALf0, const float* ALf1,
    const float* hend, const float* sumd, float* Hbuf)
{
  int gid = blockIdx.x*256 + threadIdx.x;
  int n  = gid & 15;
  int d  = (gid>>4) & 511;
  int db = gid >> 13;
  const float* ALf = (db>=8) ? ALf1 : ALf0;
  float A_dn = -__expf(ALf[d*DS + n]);
  const long base0 = (((long)db*NC)*DI + d)*16 + n;
  const long cstr  = (long)DI*16;
  const long sbase = (long)db*NC*DI + d;
  float H = 0.f;
  #pragma unroll 1
  for (int g=0; g<NC/16; g++){
    float he[16], Sv[16];
    #pragma unroll
    for (int k=0;k<16;k++){
      he[k] = hend[base0 + (long)(g*16+k)*cstr];
      Sv[k] = sumd[sbase + (long)(g*16+k)*DI];
    }
    #pragma unroll
    for (int k=0;k<16;k++){
      Hbuf[base0 + (long)(g*16+k)*cstr] = H;
      H = he[k] + __expf(A_dn*Sv[k])*H;
    }
  }
}

// ============ scan phase C: re-scan + gate only (xs/sX precomputed), d-split ============
__global__ __launch_bounds__(256, 4) void scanC_k(
    const __bf16* __restrict__ xg0, const __bf16* __restrict__ xg1,
    const float* __restrict__ sg0, const float* __restrict__ sg1,
    __bf16* __restrict__ res0, __bf16* __restrict__ res1,
    const float* __restrict__ dw0, const float* __restrict__ dw1,
    const __bf16* __restrict__ dtB0, const __bf16* __restrict__ dtB1,
    const float* __restrict__ ALf0, const float* __restrict__ ALf1,
    const __bf16* __restrict__ Dp0, const __bf16* __restrict__ Dp1,
    const float* __restrict__ Hbuf)
{
  const int zc  = blockIdx.z;       // 0..3 = dir*2 + dgroup
  const int dir = zc >> 1;
  const int dg  = zc & 1;
  const __bf16* xg  = dir ? xg1 : xg0;
  const float*  sg  = dir ? sg1 : sg0;
  __bf16*       res = dir ? res1 : res0;
  const float*  dw  = dir ? dw1 : dw0;
  const __bf16* dtB = dir ? dtB1 : dtB0;
  const float*  ALf = dir ? ALf1 : ALf0;
  const __bf16* Dp  = dir ? Dp1 : Dp0;

  const int b   = blockIdx.y;
  const int c   = blockIdx.x;       // 0..NC-1
  const int dl  = threadIdx.x;      // 0..255
  const int d   = dg*256 + dl;
  const int db  = dir*8 + b;
  const long row0 = (long)b*L_ + (long)c*CT;

  __shared__ __bf16 xs_l[CT*256];   // [32][256] bf16, row stride 512B (16KB)
  __shared__ float  sX[CT][48];     // dlt | B | C (6KB)

  // stage this block's xs sub-tile (cols dg*256..+256) via global_load_lds
  {
    const __bf16* src = xg + row0*DI + dg*256;
    #pragma unroll
    for (int i=0;i<4;i++){
      int r = i*8 + (dl>>5);
      int cs = (dl&31)*8;
      __builtin_amdgcn_global_load_lds(
        (const __attribute__((address_space(1))) void*)(src + (long)r*DI + cs),
        (__attribute__((address_space(3))) void*)(&xs_l[i*2048 + dl*8]), 16, 0, 0);
    }
  }
  // stage sX rows
  for (int v=dl; v<CT*12; v+=256)
    ((f32x4*)sX)[v] = ((const f32x4*)(sg + row0*48))[v];

  // hoist all 32 res reads (each row owned by exactly this thread; reads precede all writes)
  float rv[CT];
  #pragma unroll
  for (int t=0;t<CT;t++) rv[t] = (float)res[(row0+t)*DI + d];

  f32x2 dw2[8];
  { const f32x4* p = (const f32x4*)(dw + d*DTR);
    #pragma unroll
    for (int q=0;q<4;q++){ f32x4 v=p[q];
      dw2[q*2]   = f32x2{v[0],v[1]};
      dw2[q*2+1] = f32x2{v[2],v[3]}; } }
  float A[16];
  { const f32x4* p = (const f32x4*)(ALf + d*DS);
    #pragma unroll
    for (int q=0;q<4;q++){ f32x4 v=p[q];
      A[q*4]=-__expf(v[0]); A[q*4+1]=-__expf(v[1]); A[q*4+2]=-__expf(v[2]); A[q*4+3]=-__expf(v[3]); } }
  bool pow_ok = true;
  #pragma unroll
  for (int n=0;n<16;n++) pow_ok = pow_ok && (fabsf(A[n] + (float)(n+1)) < 0.003f*(n+1));
  const float dtbv = (float)dtB[d];
  const float Dpv  = (float)Dp[d];

  f32x2 h2[8];
  { long hb = (((long)db*NC + c)*DI + d)*16;
    const f32x4* p = (const f32x4*)(Hbuf + hb);
    #pragma unroll
    for (int q=0;q<4;q++){ f32x4 v = p[q];
      h2[q*2]   = f32x2{v[0],v[1]};
      h2[q*2+1] = f32x2{v[2],v[3]}; } }
  __syncthreads();

  if (pow_ok){
    #pragma unroll 2
    for (int t=0;t<CT;t++){
      long row = row0 + t;
      f32x2 z2 = f32x2{dtbv, 0.f};
      #pragma unroll
      for (int i=0;i<8;i++){
        f32x2 qv = *(const f32x2*)&sX[t][i*2];
        z2 += qv*dw2[i];
      }
      float delta = softplus_f(z2[0]+z2[1]);
      float xv = (float)xs_l[t*256 + dl];
      float dx = delta*xv;
      f32x2 dx2 = f32x2{dx, dx};
      float e1 = __expf(-delta), e2v = e1*e1;
      f32x2 e22 = f32x2{e2v, e2v};
      f32x2 pw = f32x2{e1, e2v};
      f32x2 p2 = f32x2{0.f, 0.f};
      #pragma unroll
      for (int i=0;i<8;i++){
        f32x2 Bv = *(const f32x2*)&sX[t][16+i*2];
        f32x2 Cv = *(const f32x2*)&sX[t][32+i*2];
        h2[i] = pw*h2[i] + dx2*Bv;
        p2 += h2[i]*Cv;
        pw = pw*e22;
      }
      float yv = p2[0] + p2[1] + Dpv*xv;
      res[row*DI + d] = (__bf16)(yv * silu_f(rv[t]));
    }
  } else {
    #pragma unroll 2
    for (int t=0;t<CT;t++){
      long row = row0 + t;
      f32x2 z2 = f32x2{dtbv, 0.f};
      #pragma unroll
      for (int i=0;i<8;i++){
        f32x2 qv = *(const f32x2*)&sX[t][i*2];
        z2 += qv*dw2[i];
      }
      float delta = softplus_f(z2[0]+z2[1]);
      float xv = (float)xs_l[t*256 + dl];
      float dx = delta*xv;
      f32x2 p2 = f32x2{0.f, 0.f};
      #pragma unroll
      for (int i=0;i<8;i++){
        f32x2 Bv = *(const f32x2*)&sX[t][16+i*2];
        f32x2 Cv = *(const f32x2*)&sX[t][32+i*2];
        f32x2 pw = f32x2{__expf(delta*A[i*2]), __expf(delta*A[i*2+1])};
        h2[i] = pw*h2[i] + f32x2{dx,dx}*Bv;
        p2 += h2[i]*Cv;
      }
      float yv = p2[0] + p2[1] + Dpv*xv;
      res[row*DI + d] = (__bf16)(yv * silu_f(rv[t]));
    }
  }
}

// ---------------- launch ----------------
extern "C" void kernel_launch(void* const* d_in, const int* in_sizes, int n_in,
                              void* d_out, int out_size, void* d_ws, size_t ws_size,
                              hipStream_t stream)
{
  const size_t MB = 1u<<20;
  if (ws_size < 160*MB) return;

  char* w = (char*)d_ws;
  __bf16* xz[2]   = {(__bf16*)(w + 0),      (__bf16*)(w + 8*MB)};
  __bf16* res[2]  = {(__bf16*)(w + 16*MB),  (__bf16*)(w + 24*MB)};
  __bf16* xs_g[2] = {(__bf16*)(w + 32*MB),  (__bf16*)(w + 40*MB)};
  __bf16* xn      = (__bf16*)(w + 48*MB);

  char* wp = w + 52*MB;
  auto carve = [&](size_t bytes)->void*{
    void* p = wp;
    wp += (bytes + 255) & ~(size_t)255;
    return p;
  };
  __bf16 *inWt[2], *xWt[2], *outWr[2], *BtC[2];
  float *dtWt[2], *convWt[2];
  for (int m=0;m<2;m++){
    inWt[m]   = (__bf16*)carve((size_t)(2*DI)*DM*2);
    xWt[m]    = (__bf16*)carve((size_t)48*DI*2);
    outWr[m]  = (__bf16*)carve((size_t)DI*DM*2);
    BtC[m]    = (__bf16*)carve((size_t)DM*DI*2);
    dtWt[m]   = (float*)carve((size_t)DI*DTR*4);
    convWt[m] = (float*)carve((size_t)4*DI*4);
  }
  __bf16* fusWt = (__bf16*)carve((size_t)DM*(2*DM)*2);
  float* ALf[2] = {(float*)carve((size_t)DI*DS*4), (float*)carve((size_t)DI*DS*4)};

  char* cp = w + 57*MB;
  auto carve2 = [&](size_t elems)->__bf16*{
    __bf16* p = (__bf16*)cp;
    cp += (elems*2 + 255) & ~(size_t)255;
    return p;
  };
  __bf16* ngc = carve2(DM);
  __bf16* nbc = carve2(DM);
  __bf16 *convBc[2], *dtBc[2], *Dpc[2];
  for (int m=0;m<2;m++){
    convBc[m] = carve2(DI);
    dtBc[m]   = carve2(DI);
    Dpc[m]    = carve2(DI);
  }
  __bf16* fusBc = carve2(DM);

  float* sXg[2] = {(float*)(w + 58*MB), (float*)(w + 60*MB)};  // 1.57MB each
  float* hend = (float*)(w + 90*MB);   // 16.8MB
  float* Hbuf = (float*)(w + 110*MB);  // 16.8MB
  float* sumd = (float*)(w + 130*MB);  // 1MB

  // elementwise prep jobs
  PrepArgs pa;
  int ji = 0;
  size_t tot = 0;
  auto addj = [&](const void* s, void* dst, int rows, int cols, int f32o){
    pa.j[ji++] = {s, dst, rows, cols, f32o};
    tot += (size_t)rows*cols;
  };
  for (int m=0;m<2;m++){
    int base = 3 + m*9;
    addj(d_in[base+3], xWt[m],   DI,  48,   0);
    addj(d_in[base+8], outWr[m], 1,   DI*DM,0);
    addj(d_in[base+4], dtWt[m],  DTR, DI,   1);
    addj(d_in[base+1], convWt[m],DI,  4,    1);
    addj(d_in[base+2], convBc[m],1, DI, 0);
    addj(d_in[base+5], dtBc[m],  1, DI, 0);
    addj(d_in[base+6], (void*)ALf[m], 1, DI*DS, 1);
    addj(d_in[base+7], Dpc[m],   1, DI, 0);
  }
  addj(d_in[1],  ngc, 1, DM, 0);
  addj(d_in[2],  nbc, 1, DM, 0);
  addj(d_in[22], fusBc, 1, DM, 0);
  pa.nj = ji;

  // tiled transpose jobs
  TArgs ta;
  ta.j[0] = { d_in[3],  inWt[0], DM,   2*DI }; ta.ntiles[0] = (DM/64)*((2*DI)/64);
  ta.j[1] = { d_in[12], inWt[1], DM,   2*DI }; ta.ntiles[1] = (DM/64)*((2*DI)/64);
  ta.j[2] = { d_in[21], fusWt,   2*DM, DM   }; ta.ntiles[2] = ((2*DM)/64)*(DM/64);
  ta.nj = 3;
  ta.ntot = ta.ntiles[0]+ta.ntiles[1]+ta.ntiles[2];
  int prepBlocks = (int)((tot+255)/256);
  wprep_k<<<ta.ntot + prepBlocks, 256, 0, stream>>>(ta, pa, d_in[0]);

  lnw_k<<<M_/4 + 64, 256, 0, stream>>>(
      d_in[0], ngc, nbc, xn, fusWt, outWr[0], outWr[1], BtC[0], BtC[1]);

  gemm_in_k<128,128,256><<<dim3(M_/128, (2*DI)/128, 2), 256, 0, stream>>>(
      xn, inWt[0], inWt[1], xz[0], xz[1], res[0], res[1], DM, DM);

  scanA_k<<<dim3(NC, B_, 2), 512, 0, stream>>>(
      xz[0], xz[1], convWt[0], convWt[1], convBc[0], convBc[1],
      xWt[0], xWt[1], dtWt[0], dtWt[1],
      dtBc[0], dtBc[1], ALf[0], ALf[1],
      xs_g[0], xs_g[1], sXg[0], sXg[1],
      hend, sumd);
  scanB_k<<<131072/256, 256, 0, stream>>>(ALf[0], ALf[1], hend, sumd, Hbuf);
  scanC_k<<<dim3(NC, B_, 4), 256, 0, stream>>>(
      xs_g[0], xs_g[1], sXg[0], sXg[1], res[0], res[1],
      dtWt[0], dtWt[1], dtBc[0], dtBc[1], ALf[0], ALf[1], Dpc[0], Dpc[1], Hbuf);

  gemm_fin_k<64,64,DI><<<dim3(M_/64, DM/64, 1), 256, 0, stream>>>(
      res[0], res[1], BtC[0], BtC[1], d_out, fusBc, d_in[0]);
}

// Round 13
// 233.962 us; speedup vs baseline: 1.0744x; 1.0744x over previous
//
#include <hip/hip_runtime.h>
#include <cmath>

typedef __bf16 bf16x8 __attribute__((ext_vector_type(8)));
typedef __bf16 bf16x4 __attribute__((ext_vector_type(4)));
typedef float  f32x4  __attribute__((ext_vector_type(4)));
typedef float  f32x2  __attribute__((ext_vector_type(2)));

#define B_  8
#define L_  1024
#define DM  256
#define DI  512
#define DS  16
#define DTR 16
#define M_  (B_*L_)
#define NC  32
#define CT  32

__device__ inline float softplus_f(float z){
  return (z > 20.f) ? z : __logf(1.f + __expf(z));
}
__device__ inline float silu_f(float z){
  return z / (1.f + __expf(-z));
}

// ---- inline dtype detector ----
__device__ inline int flag_from_x(const void* x){
  const unsigned short* u = (const unsigned short*)x;
  int lane = threadIdx.x & 63;
  unsigned short v = u[2*lane];
  int e = (v >> 7) & 0xFF;
  unsigned long long m = __ballot(e >= 160 || e < 96);
  return __popcll(m) > 16;   // 1 = inputs are fp32
}

// ---------------- unified weight prep: tiled transposes + elementwise ----------------
struct PrepJob { const void* src; void* dst; int rows; int cols; int f32out; };
struct PrepArgs { PrepJob j[26]; int nj; };
struct TJob { const void* src; __bf16* dst; int R; int C; };
struct TArgs { TJob j[3]; int ntiles[3]; int nj; int ntot; };

__global__ __launch_bounds__(256) void wprep_k(TArgs ta, PrepArgs a, const void* xsrc){
  const int f = flag_from_x(xsrc);
  const int tid = threadIdx.x;
  if ((int)blockIdx.x < ta.ntot){
    __shared__ float tile[64][65];
    int bid = blockIdx.x;
    int jj = 0;
    while (jj < ta.nj-1 && bid >= ta.ntiles[jj]) { bid -= ta.ntiles[jj]; jj++; }
    const TJob J = ta.j[jj];
    const int tpr = J.C >> 6;
    const int tr = bid / tpr, tc = bid - tr*tpr;
    const int r0 = tr*64, c0 = tc*64;
    #pragma unroll
    for (int i=0;i<16;i++){
      int idx = i*256 + tid;
      int r = idx >> 6, c = idx & 63;
      long off = (long)(r0+r)*J.C + c0 + c;
      tile[r][c] = f ? ((const float*)J.src)[off] : (float)((const __bf16*)J.src)[off];
    }
    __syncthreads();
    #pragma unroll
    for (int i=0;i<16;i++){
      int idx = i*256 + tid;
      int c = idx >> 6, r = idx & 63;
      J.dst[(long)(c0+c)*J.R + r0 + r] = (__bf16)tile[r][c];
    }
  } else {
    int e = (blockIdx.x - ta.ntot)*256 + tid;
    #pragma unroll 1
    for (int jj=0; jj<a.nj; jj++){
      int sz = a.j[jj].rows * a.j[jj].cols;
      if (e < sz){
        int cols = a.j[jj].cols;
        int r = e / cols, c = e - r*cols;
        float v = f ? ((const float*)a.j[jj].src)[e] : (float)((const __bf16*)a.j[jj].src)[e];
        if (a.j[jj].f32out) ((float*)a.j[jj].dst)[c*a.j[jj].rows + r] = v;
        else ((__bf16*)a.j[jj].dst)[(long)c*a.j[jj].rows + r] = (__bf16)v;
        return;
      }
      e -= sz;
    }
  }
}

// ---------------- LayerNorm + wcomb tail blocks ----------------
__global__ __launch_bounds__(256) void lnw_k(
    const void* x, const __bf16* g, const __bf16* bb, __bf16* xn,
    const __bf16* fusWt, const __bf16* outWr0, const __bf16* outWr1,
    __bf16* BtC0, __bf16* BtC1)
{
  const int bx = blockIdx.x;
  const int tid = threadIdx.x;
  const int lane = tid & 63;
  const int wid = tid >> 6;

  if (bx < M_/4){
    const int f = flag_from_x(x);
    long row = (long)bx*4 + wid;
    long base = row*DM + lane*4;
    float v0,v1,v2,v3;
    if (f){ f32x4 xv = *(const f32x4*)((const float*)x + base);
            v0=xv[0]; v1=xv[1]; v2=xv[2]; v3=xv[3]; }
    else  { bf16x4 xv = *(const bf16x4*)((const __bf16*)x + base);
            v0=(float)xv[0]; v1=(float)xv[1]; v2=(float)xv[2]; v3=(float)xv[3]; }
    float s = v0+v1+v2+v3;
    float q = v0*v0+v1*v1+v2*v2+v3*v3;
    #pragma unroll
    for (int off=32; off>0; off>>=1){ s += __shfl_xor(s,off); q += __shfl_xor(q,off); }
    float mu = s*(1.f/DM), var = q*(1.f/DM)-mu*mu;
    float rs = rsqrtf(var+1e-5f);
    bf16x4 gv = *(const bf16x4*)(g + lane*4);
    bf16x4 bv = *(const bf16x4*)(bb + lane*4);
    bf16x4 o;
    o[0]=(__bf16)((v0-mu)*rs*(float)gv[0]+(float)bv[0]);
    o[1]=(__bf16)((v1-mu)*rs*(float)gv[1]+(float)bv[1]);
    o[2]=(__bf16)((v2-mu)*rs*(float)gv[2]+(float)bv[2]);
    o[3]=(__bf16)((v3-mu)*rs*(float)gv[3]+(float)bv[3]);
    *(bf16x4*)(xn + base) = o;
  } else {
    int b2 = bx - M_/4;
    int wz  = b2 >> 5;
    int rem = b2 & 31;
    int gx = rem & 3, gy = rem >> 2;
    const __bf16* A  = fusWt + wz*DM;
    const __bf16* Bt = wz ? outWr1 : outWr0;
    __bf16* C = wz ? BtC1 : BtC0;
    const int mBase = (gx*4 + wid)*16;
    const int nBase = gy*64;
    const int lm = lane & 15;
    const int kq = (lane >> 4)*8;
    long aoff = (long)(mBase+lm)*(2*DM) + kq;
    long boff[4];
    #pragma unroll
    for (int j=0;j<4;j++) boff[j] = (long)(nBase+j*16+lm)*DM + kq;
    f32x4 acc[4] = {};
    #pragma unroll
    for (int k0=0;k0<DM;k0+=32){
      bf16x8 af = *(const bf16x8*)(A + aoff + k0);
      bf16x8 bfr[4];
      #pragma unroll
      for (int j=0;j<4;j++) bfr[j] = *(const bf16x8*)(Bt + boff[j] + k0);
      #pragma unroll
      for (int j=0;j<4;j++)
        acc[j] = __builtin_amdgcn_mfma_f32_16x16x32_bf16(af, bfr[j], acc[j], 0,0,0);
    }
    #pragma unroll
    for (int rr=0;rr<4;rr++){
      int r = mBase + (lane>>4)*4 + rr;
      #pragma unroll
      for (int j=0;j<4;j++){
        int c = nBase + j*16 + lm;
        C[(long)r*DI + c] = (__bf16)acc[j][rr];
      }
    }
  }
}

// ============ LDS-staged MFMA GEMM (in-proj) ============
template<int BM,int BN,int KK>
__global__ __launch_bounds__(256) void gemm_in_k(
    const __bf16* A, const __bf16* B0, const __bf16* B1,
    __bf16* xz0, __bf16* xz1, __bf16* res0, __bf16* res1,
    int lda, int ldb)
{
  constexpr int TM = BM/2, TN = BN/2;
  constexpr int WMT = TM/16, WNT = TN/16;
  constexpr int LA = BM/64, LB = BN/64;

  const int dir = blockIdx.z;
  const __bf16* Bt = dir ? B1 : B0;
  __bf16* xz  = dir ? xz1 : xz0;
  __bf16* res = dir ? res1 : res0;
  const int tid  = threadIdx.x;
  const int lane = tid & 63;
  const int wid  = tid >> 6;
  const int wm = wid & 1;
  const int wn = wid >> 1;
  const int mBase = blockIdx.x * BM;
  const int nBase = blockIdx.y * BN;
  const int lm = lane & 15;
  const int kq = (lane >> 4) * 8;

  __shared__ __bf16 As[BM*32];
  __shared__ __bf16 Bs[BN*32];

  const __bf16* aS[LA];
  const __bf16* bS[LB];
  {
    int colk = (tid & 3) * 8;
    #pragma unroll
    for (int ld=0; ld<LA; ld++){
      int r = mBase + ld*64 + (tid >> 2);
      if (dir==1){ int b = r >> 10, t = r & (L_-1); r = (b<<10) + (L_-1-t); }
      aS[ld] = A + (long)r*lda + colk;
    }
    #pragma unroll
    for (int ld=0; ld<LB; ld++){
      int r = nBase + ld*64 + (tid >> 2);
      bS[ld] = Bt + (long)r*ldb + colk;
    }
  }

  f32x4 acc[WMT][WNT] = {};
  for (int k0=0; k0<KK; k0+=32){
    #pragma unroll
    for (int ld=0; ld<LA; ld++)
      __builtin_amdgcn_global_load_lds(
        (const __attribute__((address_space(1))) void*)(aS[ld] + k0),
        (__attribute__((address_space(3))) void*)(&As[ld*2048 + tid*8]), 16, 0, 0);
    #pragma unroll
    for (int ld=0; ld<LB; ld++)
      __builtin_amdgcn_global_load_lds(
        (const __attribute__((address_space(1))) void*)(bS[ld] + k0),
        (__attribute__((address_space(3))) void*)(&Bs[ld*2048 + tid*8]), 16, 0, 0);
    __syncthreads();
    bf16x8 af[WMT], bfr[WNT];
    #pragma unroll
    for (int i=0;i<WMT;i++) af[i]  = *(const bf16x8*)&As[(wm*TM + i*16 + lm)*32 + kq];
    #pragma unroll
    for (int j=0;j<WNT;j++) bfr[j] = *(const bf16x8*)&Bs[(wn*TN + j*16 + lm)*32 + kq];
    #pragma unroll
    for (int i=0;i<WMT;i++)
      #pragma unroll
      for (int j=0;j<WNT;j++)
        acc[i][j] = __builtin_amdgcn_mfma_f32_16x16x32_bf16(af[i], bfr[j], acc[i][j], 0,0,0);
    __syncthreads();
  }

  #pragma unroll
  for (int i=0;i<WMT;i++){
    #pragma unroll
    for (int rr=0;rr<4;rr++){
      int r = mBase + wm*TM + i*16 + (lane>>4)*4 + rr;
      #pragma unroll
      for (int j=0;j<WNT;j++){
        int c = nBase + wn*TN + j*16 + lm;
        float v = acc[i][j][rr];
        if (c < DI) xz[(long)r*DI + c] = (__bf16)v;
        else        res[(long)r*DI + (c-DI)] = (__bf16)v;
      }
    }
  }
}

// ============ final fused GEMM ============
template<int BM,int BN,int KK>
__global__ __launch_bounds__(256) void gemm_fin_k(
    const __bf16* Af, const __bf16* Ab,
    const __bf16* Bt0, const __bf16* Bt1,
    void* Cout, const __bf16* bias, const void* resid)
{
  constexpr int TM = BM/2, TN = BN/2;
  constexpr int WMT = TM/16, WNT = TN/16;
  constexpr int LA = BM/64, LB = BN/64;

  const int of = flag_from_x(resid);
  const int tid  = threadIdx.x;
  const int lane = tid & 63;
  const int wid  = tid >> 6;
  const int wm = wid & 1;
  const int wn = wid >> 1;
  const int mBase = blockIdx.x * BM;
  const int nBase = blockIdx.y * BN;
  const int lm = lane & 15;
  const int kq = (lane >> 4) * 8;

  __shared__ __bf16 As[BM*32];
  __shared__ __bf16 Bs[BN*32];

  f32x4 acc[WMT][WNT] = {};
  #pragma unroll 1
  for (int dd=0; dd<2; dd++){
    const __bf16* A  = dd ? Ab  : Af;
    const __bf16* Bt = dd ? Bt1 : Bt0;
    const __bf16* aS[LA];
    const __bf16* bS[LB];
    {
      int colk = (tid & 3) * 8;
      #pragma unroll
      for (int ld=0; ld<LA; ld++){
        int r = mBase + ld*64 + (tid >> 2);
        if (dd==1){ int b = r >> 10, t = r & (L_-1); r = (b<<10) + (L_-1-t); }
        aS[ld] = A + (long)r*DI + colk;
      }
      #pragma unroll
      for (int ld=0; ld<LB; ld++){
        int r = nBase + ld*64 + (tid >> 2);
        bS[ld] = Bt + (long)r*DI + colk;
      }
    }
    for (int k0=0; k0<KK; k0+=32){
      #pragma unroll
      for (int ld=0; ld<LA; ld++)
        __builtin_amdgcn_global_load_lds(
          (const __attribute__((address_space(1))) void*)(aS[ld] + k0),
          (__attribute__((address_space(3))) void*)(&As[ld*2048 + tid*8]), 16, 0, 0);
      #pragma unroll
      for (int ld=0; ld<LB; ld++)
        __builtin_amdgcn_global_load_lds(
          (const __attribute__((address_space(1))) void*)(bS[ld] + k0),
          (__attribute__((address_space(3))) void*)(&Bs[ld*2048 + tid*8]), 16, 0, 0);
      __syncthreads();
      bf16x8 af[WMT], bfr[WNT];
      #pragma unroll
      for (int i=0;i<WMT;i++) af[i]  = *(const bf16x8*)&As[(wm*TM + i*16 + lm)*32 + kq];
      #pragma unroll
      for (int j=0;j<WNT;j++) bfr[j] = *(const bf16x8*)&Bs[(wn*TN + j*16 + lm)*32 + kq];
      #pragma unroll
      for (int i=0;i<WMT;i++)
        #pragma unroll
        for (int j=0;j<WNT;j++)
          acc[i][j] = __builtin_amdgcn_mfma_f32_16x16x32_bf16(af[i], bfr[j], acc[i][j], 0,0,0);
      __syncthreads();
    }
  }

  #pragma unroll
  for (int i=0;i<WMT;i++){
    #pragma unroll
    for (int rr=0;rr<4;rr++){
      int r = mBase + wm*TM + i*16 + (lane>>4)*4 + rr;
      #pragma unroll
      for (int j=0;j<WNT;j++){
        int c = nBase + wn*TN + j*16 + lm;
        float v = acc[i][j][rr];
        float rsd = of ? ((const float*)resid)[(long)r*DM + c]
                       : (float)((const __bf16*)resid)[(long)r*DM + c];
        v += (float)bias[c] + rsd;
        if (of) ((float*)Cout)[(long)r*DM + c] = v;
        else    ((__bf16*)Cout)[(long)r*DM + c] = (__bf16)v;
      }
    }
  }
}

// ============ scan phase A: conv + x-proj MFMA + local scan, with xs/sX write-through ============
__global__ __launch_bounds__(512) void scanA_k(
    const __bf16* xz0, const __bf16* xz1,
    const float* cw0, const float* cw1,
    const __bf16* cb0, const __bf16* cb1,
    const __bf16* xW0, const __bf16* xW1,
    const float* dw0, const float* dw1,
    const __bf16* dtB0, const __bf16* dtB1,
    const float* ALf0, const float* ALf1,
    __bf16* xg0, __bf16* xg1,
    float* sg0, float* sg1,
    float* hend, float* sumd)
{
  const int dir = blockIdx.z;
  const __bf16* xz  = dir ? xz1 : xz0;
  const float*  cw  = dir ? cw1 : cw0;
  const __bf16* cb  = dir ? cb1 : cb0;
  const __bf16* xWt = dir ? xW1 : xW0;
  const float*  dw  = dir ? dw1 : dw0;
  const __bf16* dtB = dir ? dtB1 : dtB0;
  const float*  ALf = dir ? ALf1 : ALf0;
  __bf16*       xg  = dir ? xg1 : xg0;
  float*        sg  = dir ? sg1 : sg0;

  const int b   = blockIdx.y;
  const int c   = blockIdx.x;
  const int tid = threadIdx.x;
  const int lane = tid & 63;
  const int wid  = tid >> 6;
  const int d   = tid;
  const int db  = dir*8 + b;
  const long row0 = (long)b*L_ + (long)c*CT;

  __shared__ __bf16 xs_s[CT*DI];    // 32KB, XOR-swizzled, row stride 1024B
  __shared__ float  sX[CT][48];     // dlt | B | C

  // ---- conv + silu -> xs LDS + global write-through (load-all-first) ----
  {
    const float q0 = cw[0*DI+d], q1 = cw[1*DI+d], q2 = cw[2*DI+d], q3 = cw[3*DI+d];
    const float cbv = (float)cb[d];
    int gt0 = c*CT;
    float xt[CT];
    #pragma unroll
    for (int t=0;t<CT;t++) xt[t] = (float)xz[(row0+t)*DI + d];
    float xm3 = (gt0-3 >= 0) ? (float)xz[(row0-3)*DI + d] : 0.f;
    float xm2 = (gt0-2 >= 0) ? (float)xz[(row0-2)*DI + d] : 0.f;
    float xm1 = (gt0-1 >= 0) ? (float)xz[(row0-1)*DI + d] : 0.f;
    #pragma unroll
    for (int t=0;t<CT;t++){
      float av = cbv;
      av += xm3*q0; av += xm2*q1; av += xm1*q2; av += xt[t]*q3;
      __bf16 sv = (__bf16)silu_f(av);
      *(__bf16*)((char*)xs_s + t*1024 + ((2*d) ^ ((t&7)<<4))) = sv;
      xg[(row0+t)*DI + d] = sv;
      xm3 = xm2; xm2 = xm1; xm1 = xt[t];
    }
  }
  __syncthreads();

  // ---- x-proj: sX[32][48] = xs[32][512] @ xW^T  (6 waves) + global write-through ----
  if (wid < 6){
    const int mb = (wid & 1) * 16;
    const int nb = (wid >> 1) * 16;
    const int lm = lane & 15;
    const int kq = (lane >> 4) * 8;
    const int row = mb + lm;
    const char* abase = (const char*)xs_s + row*1024;
    const int rsw = (row&7)<<4;
    const __bf16* Bt = xWt + (long)(nb + lm)*DI + kq;
    f32x4 acc = {};
    #pragma unroll
    for (int k0=0;k0<DI;k0+=32){
      bf16x8 af  = *(const bf16x8*)(abase + (((kq + k0)*2) ^ rsw));
      bf16x8 bfr = *(const bf16x8*)(Bt + k0);
      acc = __builtin_amdgcn_mfma_f32_16x16x32_bf16(af, bfr, acc, 0,0,0);
    }
    #pragma unroll
    for (int rr=0;rr<4;rr++){
      int r = mb + (lane>>4)*4 + rr;
      sX[r][nb + lm] = acc[rr];
      sg[(row0 + r)*48 + nb + lm] = acc[rr];
    }
  }

  // ---- per-thread scan state ----
  f32x2 dw2[8];
  { const f32x4* p = (const f32x4*)(dw + d*DTR);
    #pragma unroll
    for (int q=0;q<4;q++){ f32x4 v=p[q];
      dw2[q*2]   = f32x2{v[0],v[1]};
      dw2[q*2+1] = f32x2{v[2],v[3]}; } }
  float A[16];
  { const f32x4* p = (const f32x4*)(ALf + d*DS);
    #pragma unroll
    for (int q=0;q<4;q++){ f32x4 v=p[q];
      A[q*4]=-__expf(v[0]); A[q*4+1]=-__expf(v[1]); A[q*4+2]=-__expf(v[2]); A[q*4+3]=-__expf(v[3]); } }
  bool pow_ok = true;
  #pragma unroll
  for (int n=0;n<16;n++) pow_ok = pow_ok && (fabsf(A[n] + (float)(n+1)) < 0.003f*(n+1));
  const float dtbv = (float)dtB[d];

  f32x2 h2[8];
  #pragma unroll
  for (int i=0;i<8;i++) h2[i] = f32x2{0.f,0.f};
  float sdelta = 0.f;
  __syncthreads();

  if (pow_ok){
    #pragma unroll 2
    for (int t=0;t<CT;t++){
      f32x2 z2 = f32x2{dtbv, 0.f};
      #pragma unroll
      for (int i=0;i<8;i++){
        f32x2 qv = *(const f32x2*)&sX[t][i*2];
        z2 += qv*dw2[i];
      }
      float delta = softplus_f(z2[0]+z2[1]);
      sdelta += delta;
      float xv = (float)*(const __bf16*)((const char*)xs_s + t*1024 + ((2*d) ^ ((t&7)<<4)));
      float dx = delta*xv;
      f32x2 dx2 = f32x2{dx, dx};
      float e1 = __expf(-delta), e2v = e1*e1;
      f32x2 e22 = f32x2{e2v, e2v};
      f32x2 pw = f32x2{e1, e2v};
      #pragma unroll
      for (int i=0;i<8;i++){
        f32x2 Bv = *(const f32x2*)&sX[t][16+i*2];
        h2[i] = pw*h2[i] + dx2*Bv;
        pw = pw*e22;
      }
    }
  } else {
    #pragma unroll 2
    for (int t=0;t<CT;t++){
      f32x2 z2 = f32x2{dtbv, 0.f};
      #pragma unroll
      for (int i=0;i<8;i++){
        f32x2 qv = *(const f32x2*)&sX[t][i*2];
        z2 += qv*dw2[i];
      }
      float delta = softplus_f(z2[0]+z2[1]);
      sdelta += delta;
      float xv = (float)*(const __bf16*)((const char*)xs_s + t*1024 + ((2*d) ^ ((t&7)<<4)));
      float dx = delta*xv;
      #pragma unroll
      for (int i=0;i<8;i++){
        f32x2 Bv = *(const f32x2*)&sX[t][16+i*2];
        f32x2 pw = f32x2{__expf(delta*A[i*2]), __expf(delta*A[i*2+1])};
        h2[i] = pw*h2[i] + f32x2{dx,dx}*Bv;
      }
    }
  }

  long hb = (((long)db*NC + c)*DI + d)*16;
  f32x4* hp = (f32x4*)(hend + hb);
  #pragma unroll
  for (int q=0;q<4;q++){
    f32x4 v; v[0]=h2[q*2][0]; v[1]=h2[q*2][1]; v[2]=h2[q*2+1][0]; v[3]=h2[q*2+1][1];
    hp[q]=v;
  }
  sumd[((long)db*NC + c)*DI + d] = sdelta;
}

// ============ phase B: cross-chunk scan, register-prefetched ============
__global__ __launch_bounds__(256) void scanB_k(
    const float* ALf0, const float* ALf1,
    const float* hend, const float* sumd, float* Hbuf)
{
  int gid = blockIdx.x*256 + threadIdx.x;
  int n  = gid & 15;
  int d  = (gid>>4) & 511;
  int db = gid >> 13;
  const float* ALf = (db>=8) ? ALf1 : ALf0;
  float A_dn = -__expf(ALf[d*DS + n]);
  const long base0 = (((long)db*NC)*DI + d)*16 + n;
  const long cstr  = (long)DI*16;
  const long sbase = (long)db*NC*DI + d;
  float H = 0.f;
  #pragma unroll 1
  for (int g=0; g<NC/16; g++){
    float he[16], Sv[16];
    #pragma unroll
    for (int k=0;k<16;k++){
      he[k] = hend[base0 + (long)(g*16+k)*cstr];
      Sv[k] = sumd[sbase + (long)(g*16+k)*DI];
    }
    #pragma unroll
    for (int k=0;k<16;k++){
      Hbuf[base0 + (long)(g*16+k)*cstr] = H;
      H = he[k] + __expf(A_dn*Sv[k])*H;
    }
  }
}

// ============ scan phase C: re-scan + gate only (xs/sX/res staged via LDS), d-split ============
__global__ __launch_bounds__(256, 4) void scanC_k(
    const __bf16* __restrict__ xg0, const __bf16* __restrict__ xg1,
    const float* __restrict__ sg0, const float* __restrict__ sg1,
    __bf16* __restrict__ res0, __bf16* __restrict__ res1,
    const float* __restrict__ dw0, const float* __restrict__ dw1,
    const __bf16* __restrict__ dtB0, const __bf16* __restrict__ dtB1,
    const float* __restrict__ ALf0, const float* __restrict__ ALf1,
    const __bf16* __restrict__ Dp0, const __bf16* __restrict__ Dp1,
    const float* __restrict__ Hbuf)
{
  const int zc  = blockIdx.z;       // 0..3 = dir*2 + dgroup
  const int dir = zc >> 1;
  const int dg  = zc & 1;
  const __bf16* xg  = dir ? xg1 : xg0;
  const float*  sg  = dir ? sg1 : sg0;
  __bf16*       res = dir ? res1 : res0;
  const float*  dw  = dir ? dw1 : dw0;
  const __bf16* dtB = dir ? dtB1 : dtB0;
  const float*  ALf = dir ? ALf1 : ALf0;
  const __bf16* Dp  = dir ? Dp1 : Dp0;

  const int b   = blockIdx.y;
  const int c   = blockIdx.x;       // 0..NC-1
  const int dl  = threadIdx.x;      // 0..255
  const int d   = dg*256 + dl;
  const int db  = dir*8 + b;
  const long row0 = (long)b*L_ + (long)c*CT;

  __shared__ __bf16 xs_l[CT*256];   // [32][256] bf16, row stride 512B (16KB)
  __shared__ __bf16 rs_l[CT*256];   // res gate tile, same layout (16KB)
  __shared__ float  sX[CT][48];     // dlt | B | C (6KB)  -> total 38.5KB, 4 blocks/CU ok

  // stage xs and res sub-tiles (cols dg*256..+256) via global_load_lds (coalesced, async)
  {
    const __bf16* srcx = xg  + row0*DI + dg*256;
    const __bf16* srcr = res + row0*DI + dg*256;
    #pragma unroll
    for (int i=0;i<4;i++){
      int r = i*8 + (dl>>5);
      int cs = (dl&31)*8;
      __builtin_amdgcn_global_load_lds(
        (const __attribute__((address_space(1))) void*)(srcx + (long)r*DI + cs),
        (__attribute__((address_space(3))) void*)(&xs_l[i*2048 + dl*8]), 16, 0, 0);
      __builtin_amdgcn_global_load_lds(
        (const __attribute__((address_space(1))) void*)(srcr + (long)r*DI + cs),
        (__attribute__((address_space(3))) void*)(&rs_l[i*2048 + dl*8]), 16, 0, 0);
    }
  }
  // stage sX rows
  for (int v=dl; v<CT*12; v+=256)
    ((f32x4*)sX)[v] = ((const f32x4*)(sg + row0*48))[v];

  f32x2 dw2[8];
  { const f32x4* p = (const f32x4*)(dw + d*DTR);
    #pragma unroll
    for (int q=0;q<4;q++){ f32x4 v=p[q];
      dw2[q*2]   = f32x2{v[0],v[1]};
      dw2[q*2+1] = f32x2{v[2],v[3]}; } }
  float A[16];
  { const f32x4* p = (const f32x4*)(ALf + d*DS);
    #pragma unroll
    for (int q=0;q<4;q++){ f32x4 v=p[q];
      A[q*4]=-__expf(v[0]); A[q*4+1]=-__expf(v[1]); A[q*4+2]=-__expf(v[2]); A[q*4+3]=-__expf(v[3]); } }
  bool pow_ok = true;
  #pragma unroll
  for (int n=0;n<16;n++) pow_ok = pow_ok && (fabsf(A[n] + (float)(n+1)) < 0.003f*(n+1));
  const float dtbv = (float)dtB[d];
  const float Dpv  = (float)Dp[d];

  f32x2 h2[8];
  { long hb = (((long)db*NC + c)*DI + d)*16;
    const f32x4* p = (const f32x4*)(Hbuf + hb);
    #pragma unroll
    for (int q=0;q<4;q++){ f32x4 v = p[q];
      h2[q*2]   = f32x2{v[0],v[1]};
      h2[q*2+1] = f32x2{v[2],v[3]}; } }
  __syncthreads();

  if (pow_ok){
    #pragma unroll 2
    for (int t=0;t<CT;t++){
      long row = row0 + t;
      f32x2 z2 = f32x2{dtbv, 0.f};
      #pragma unroll
      for (int i=0;i<8;i++){
        f32x2 qv = *(const f32x2*)&sX[t][i*2];
        z2 += qv*dw2[i];
      }
      float delta = softplus_f(z2[0]+z2[1]);
      float xv = (float)xs_l[t*256 + dl];
      float dx = delta*xv;
      f32x2 dx2 = f32x2{dx, dx};
      float e1 = __expf(-delta), e2v = e1*e1;
      f32x2 e22 = f32x2{e2v, e2v};
      f32x2 pw = f32x2{e1, e2v};
      f32x2 p2 = f32x2{0.f, 0.f};
      #pragma unroll
      for (int i=0;i<8;i++){
        f32x2 Bv = *(const f32x2*)&sX[t][16+i*2];
        f32x2 Cv = *(const f32x2*)&sX[t][32+i*2];
        h2[i] = pw*h2[i] + dx2*Bv;
        p2 += h2[i]*Cv;
        pw = pw*e22;
      }
      float yv = p2[0] + p2[1] + Dpv*xv;
      float rv = (float)rs_l[t*256 + dl];
      res[row*DI + d] = (__bf16)(yv * silu_f(rv));
    }
  } else {
    #pragma unroll 2
    for (int t=0;t<CT;t++){
      long row = row0 + t;
      f32x2 z2 = f32x2{dtbv, 0.f};
      #pragma unroll
      for (int i=0;i<8;i++){
        f32x2 qv = *(const f32x2*)&sX[t][i*2];
        z2 += qv*dw2[i];
      }
      float delta = softplus_f(z2[0]+z2[1]);
      float xv = (float)xs_l[t*256 + dl];
      float dx = delta*xv;
      f32x2 p2 = f32x2{0.f, 0.f};
      #pragma unroll
      for (int i=0;i<8;i++){
        f32x2 Bv = *(const f32x2*)&sX[t][16+i*2];
        f32x2 Cv = *(const f32x2*)&sX[t][32+i*2];
        f32x2 pw = f32x2{__expf(delta*A[i*2]), __expf(delta*A[i*2+1])};
        h2[i] = pw*h2[i] + f32x2{dx,dx}*Bv;
        p2 += h2[i]*Cv;
      }
      float yv = p2[0] + p2[1] + Dpv*xv;
      float rv = (float)rs_l[t*256 + dl];
      res[row*DI + d] = (__bf16)(yv * silu_f(rv));
    }
  }
}

// ---------------- launch ----------------
extern "C" void kernel_launch(void* const* d_in, const int* in_sizes, int n_in,
                              void* d_out, int out_size, void* d_ws, size_t ws_size,
                              hipStream_t stream)
{
  const size_t MB = 1u<<20;
  if (ws_size < 160*MB) return;

  char* w = (char*)d_ws;
  __bf16* xz[2]   = {(__bf16*)(w + 0),      (__bf16*)(w + 8*MB)};
  __bf16* res[2]  = {(__bf16*)(w + 16*MB),  (__bf16*)(w + 24*MB)};
  __bf16* xs_g[2] = {(__bf16*)(w + 32*MB),  (__bf16*)(w + 40*MB)};
  __bf16* xn      = (__bf16*)(w + 48*MB);

  char* wp = w + 52*MB;
  auto carve = [&](size_t bytes)->void*{
    void* p = wp;
    wp += (bytes + 255) & ~(size_t)255;
    return p;
  };
  __bf16 *inWt[2], *xWt[2], *outWr[2], *BtC[2];
  float *dtWt[2], *convWt[2];
  for (int m=0;m<2;m++){
    inWt[m]   = (__bf16*)carve((size_t)(2*DI)*DM*2);
    xWt[m]    = (__bf16*)carve((size_t)48*DI*2);
    outWr[m]  = (__bf16*)carve((size_t)DI*DM*2);
    BtC[m]    = (__bf16*)carve((size_t)DM*DI*2);
    dtWt[m]   = (float*)carve((size_t)DI*DTR*4);
    convWt[m] = (float*)carve((size_t)4*DI*4);
  }
  __bf16* fusWt = (__bf16*)carve((size_t)DM*(2*DM)*2);
  float* ALf[2] = {(float*)carve((size_t)DI*DS*4), (float*)carve((size_t)DI*DS*4)};

  char* cp = w + 57*MB;
  auto carve2 = [&](size_t elems)->__bf16*{
    __bf16* p = (__bf16*)cp;
    cp += (elems*2 + 255) & ~(size_t)255;
    return p;
  };
  __bf16* ngc = carve2(DM);
  __bf16* nbc = carve2(DM);
  __bf16 *convBc[2], *dtBc[2], *Dpc[2];
  for (int m=0;m<2;m++){
    convBc[m] = carve2(DI);
    dtBc[m]   = carve2(DI);
    Dpc[m]    = carve2(DI);
  }
  __bf16* fusBc = carve2(DM);

  float* sXg[2] = {(float*)(w + 58*MB), (float*)(w + 60*MB)};  // 1.57MB each
  float* hend = (float*)(w + 90*MB);   // 16.8MB
  float* Hbuf = (float*)(w + 110*MB);  // 16.8MB
  float* sumd = (float*)(w + 130*MB);  // 1MB

  // elementwise prep jobs
  PrepArgs pa;
  int ji = 0;
  size_t tot = 0;
  auto addj = [&](const void* s, void* dst, int rows, int cols, int f32o){
    pa.j[ji++] = {s, dst, rows, cols, f32o};
    tot += (size_t)rows*cols;
  };
  for (int m=0;m<2;m++){
    int base = 3 + m*9;
    addj(d_in[base+3], xWt[m],   DI,  48,   0);
    addj(d_in[base+8], outWr[m], 1,   DI*DM,0);
    addj(d_in[base+4], dtWt[m],  DTR, DI,   1);
    addj(d_in[base+1], convWt[m],DI,  4,    1);
    addj(d_in[base+2], convBc[m],1, DI, 0);
    addj(d_in[base+5], dtBc[m],  1, DI, 0);
    addj(d_in[base+6], (void*)ALf[m], 1, DI*DS, 1);
    addj(d_in[base+7], Dpc[m],   1, DI, 0);
  }
  addj(d_in[1],  ngc, 1, DM, 0);
  addj(d_in[2],  nbc, 1, DM, 0);
  addj(d_in[22], fusBc, 1, DM, 0);
  pa.nj = ji;

  // tiled transpose jobs
  TArgs ta;
  ta.j[0] = { d_in[3],  inWt[0], DM,   2*DI }; ta.ntiles[0] = (DM/64)*((2*DI)/64);
  ta.j[1] = { d_in[12], inWt[1], DM,   2*DI }; ta.ntiles[1] = (DM/64)*((2*DI)/64);
  ta.j[2] = { d_in[21], fusWt,   2*DM, DM   }; ta.ntiles[2] = ((2*DM)/64)*(DM/64);
  ta.nj = 3;
  ta.ntot = ta.ntiles[0]+ta.ntiles[1]+ta.ntiles[2];
  int prepBlocks = (int)((tot+255)/256);
  wprep_k<<<ta.ntot + prepBlocks, 256, 0, stream>>>(ta, pa, d_in[0]);

  lnw_k<<<M_/4 + 64, 256, 0, stream>>>(
      d_in[0], ngc, nbc, xn, fusWt, outWr[0], outWr[1], BtC[0], BtC[1]);

  gemm_in_k<128,128,256><<<dim3(M_/128, (2*DI)/128, 2), 256, 0, stream>>>(
      xn, inWt[0], inWt[1], xz[0], xz[1], res[0], res[1], DM, DM);

  scanA_k<<<dim3(NC, B_, 2), 512, 0, stream>>>(
      xz[0], xz[1], convWt[0], convWt[1], convBc[0], convBc[1],
      xWt[0], xWt[1], dtWt[0], dtWt[1],
      dtBc[0], dtBc[1], ALf[0], ALf[1],
      xs_g[0], xs_g[1], sXg[0], sXg[1],
      hend, sumd);
  scanB_k<<<131072/256, 256, 0, stream>>>(ALf[0], ALf[1], hend, sumd, Hbuf);
  scanC_k<<<dim3(NC, B_, 4), 256, 0, stream>>>(
      xs_g[0], xs_g[1], sXg[0], sXg[1], res[0], res[1],
      dtWt[0], dtWt[1], dtBc[0], dtBc[1], ALf[0], ALf[1], Dpc[0], Dpc[1], Hbuf);

  gemm_fin_k<64,64,DI><<<dim3(M_/64, DM/64, 1), 256, 0, stream>>>(
      res[0], res[1], BtC[0], BtC[1], d_out, fusBc, d_in[0]);
}

// Round 14
// 230.522 us; speedup vs baseline: 1.0904x; 1.0149x over previous
//
#include <hip/hip_runtime.h>
#include <cmath>

typedef __bf16 bf16x8 __attribute__((ext_vector_type(8)));
typedef __bf16 bf16x4 __attribute__((ext_vector_type(4)));
typedef float  f32x4  __attribute__((ext_vector_type(4)));
typedef float  f32x2  __attribute__((ext_vector_type(2)));

#define B_  8
#define L_  1024
#define DM  256
#define DI  512
#define DS  16
#define DTR 16
#define M_  (B_*L_)
#define NC  32
#define CT  32

__device__ inline float softplus_f(float z){
  return (z > 20.f) ? z : __logf(1.f + __expf(z));
}
__device__ inline float silu_f(float z){
  return z / (1.f + __expf(-z));
}

// ---- inline dtype detector ----
__device__ inline int flag_from_x(const void* x){
  const unsigned short* u = (const unsigned short*)x;
  int lane = threadIdx.x & 63;
  unsigned short v = u[2*lane];
  int e = (v >> 7) & 0xFF;
  unsigned long long m = __ballot(e >= 160 || e < 96);
  return __popcll(m) > 16;   // 1 = inputs are fp32
}

// ---------------- unified weight prep: tiled transposes + elementwise ----------------
struct PrepJob { const void* src; void* dst; int rows; int cols; int f32out; };
struct PrepArgs { PrepJob j[26]; int nj; };
struct TJob { const void* src; __bf16* dst; int R; int C; };
struct TArgs { TJob j[3]; int ntiles[3]; int nj; int ntot; };

__global__ __launch_bounds__(256) void wprep_k(TArgs ta, PrepArgs a, const void* xsrc){
  const int f = flag_from_x(xsrc);
  const int tid = threadIdx.x;
  if ((int)blockIdx.x < ta.ntot){
    __shared__ float tile[64][65];
    int bid = blockIdx.x;
    int jj = 0;
    while (jj < ta.nj-1 && bid >= ta.ntiles[jj]) { bid -= ta.ntiles[jj]; jj++; }
    const TJob J = ta.j[jj];
    const int tpr = J.C >> 6;
    const int tr = bid / tpr, tc = bid - tr*tpr;
    const int r0 = tr*64, c0 = tc*64;
    #pragma unroll
    for (int i=0;i<16;i++){
      int idx = i*256 + tid;
      int r = idx >> 6, c = idx & 63;
      long off = (long)(r0+r)*J.C + c0 + c;
      tile[r][c] = f ? ((const float*)J.src)[off] : (float)((const __bf16*)J.src)[off];
    }
    __syncthreads();
    #pragma unroll
    for (int i=0;i<16;i++){
      int idx = i*256 + tid;
      int c = idx >> 6, r = idx & 63;
      J.dst[(long)(c0+c)*J.R + r0 + r] = (__bf16)tile[r][c];
    }
  } else {
    int e = (blockIdx.x - ta.ntot)*256 + tid;
    #pragma unroll 1
    for (int jj=0; jj<a.nj; jj++){
      int sz = a.j[jj].rows * a.j[jj].cols;
      if (e < sz){
        int cols = a.j[jj].cols;
        int r = e / cols, c = e - r*cols;
        float v = f ? ((const float*)a.j[jj].src)[e] : (float)((const __bf16*)a.j[jj].src)[e];
        if (a.j[jj].f32out) ((float*)a.j[jj].dst)[c*a.j[jj].rows + r] = v;
        else ((__bf16*)a.j[jj].dst)[(long)c*a.j[jj].rows + r] = (__bf16)v;
        return;
      }
      e -= sz;
    }
  }
}

// ---------------- LayerNorm + wcomb tail blocks ----------------
__global__ __launch_bounds__(256) void lnw_k(
    const void* x, const __bf16* g, const __bf16* bb, __bf16* xn,
    const __bf16* fusWt, const __bf16* outWr0, const __bf16* outWr1,
    __bf16* BtC0, __bf16* BtC1)
{
  const int bx = blockIdx.x;
  const int tid = threadIdx.x;
  const int lane = tid & 63;
  const int wid = tid >> 6;

  if (bx < M_/4){
    const int f = flag_from_x(x);
    long row = (long)bx*4 + wid;
    long base = row*DM + lane*4;
    float v0,v1,v2,v3;
    if (f){ f32x4 xv = *(const f32x4*)((const float*)x + base);
            v0=xv[0]; v1=xv[1]; v2=xv[2]; v3=xv[3]; }
    else  { bf16x4 xv = *(const bf16x4*)((const __bf16*)x + base);
            v0=(float)xv[0]; v1=(float)xv[1]; v2=(float)xv[2]; v3=(float)xv[3]; }
    float s = v0+v1+v2+v3;
    float q = v0*v0+v1*v1+v2*v2+v3*v3;
    #pragma unroll
    for (int off=32; off>0; off>>=1){ s += __shfl_xor(s,off); q += __shfl_xor(q,off); }
    float mu = s*(1.f/DM), var = q*(1.f/DM)-mu*mu;
    float rs = rsqrtf(var+1e-5f);
    bf16x4 gv = *(const bf16x4*)(g + lane*4);
    bf16x4 bv = *(const bf16x4*)(bb + lane*4);
    bf16x4 o;
    o[0]=(__bf16)((v0-mu)*rs*(float)gv[0]+(float)bv[0]);
    o[1]=(__bf16)((v1-mu)*rs*(float)gv[1]+(float)bv[1]);
    o[2]=(__bf16)((v2-mu)*rs*(float)gv[2]+(float)bv[2]);
    o[3]=(__bf16)((v3-mu)*rs*(float)gv[3]+(float)bv[3]);
    *(bf16x4*)(xn + base) = o;
  } else {
    int b2 = bx - M_/4;
    int wz  = b2 >> 5;
    int rem = b2 & 31;
    int gx = rem & 3, gy = rem >> 2;
    const __bf16* A  = fusWt + wz*DM;
    const __bf16* Bt = wz ? outWr1 : outWr0;
    __bf16* C = wz ? BtC1 : BtC0;
    const int mBase = (gx*4 + wid)*16;
    const int nBase = gy*64;
    const int lm = lane & 15;
    const int kq = (lane >> 4)*8;
    long aoff = (long)(mBase+lm)*(2*DM) + kq;
    long boff[4];
    #pragma unroll
    for (int j=0;j<4;j++) boff[j] = (long)(nBase+j*16+lm)*DM + kq;
    f32x4 acc[4] = {};
    #pragma unroll
    for (int k0=0;k0<DM;k0+=32){
      bf16x8 af = *(const bf16x8*)(A + aoff + k0);
      bf16x8 bfr[4];
      #pragma unroll
      for (int j=0;j<4;j++) bfr[j] = *(const bf16x8*)(Bt + boff[j] + k0);
      #pragma unroll
      for (int j=0;j<4;j++)
        acc[j] = __builtin_amdgcn_mfma_f32_16x16x32_bf16(af, bfr[j], acc[j], 0,0,0);
    }
    #pragma unroll
    for (int rr=0;rr<4;rr++){
      int r = mBase + (lane>>4)*4 + rr;
      #pragma unroll
      for (int j=0;j<4;j++){
        int c = nBase + j*16 + lm;
        C[(long)r*DI + c] = (__bf16)acc[j][rr];
      }
    }
  }
}

// ============ LDS-staged MFMA GEMM (in-proj) ============
template<int BM,int BN,int KK>
__global__ __launch_bounds__(256) void gemm_in_k(
    const __bf16* A, const __bf16* B0, const __bf16* B1,
    __bf16* xz0, __bf16* xz1, __bf16* res0, __bf16* res1,
    int lda, int ldb)
{
  constexpr int TM = BM/2, TN = BN/2;
  constexpr int WMT = TM/16, WNT = TN/16;
  constexpr int LA = BM/64, LB = BN/64;

  const int dir = blockIdx.z;
  const __bf16* Bt = dir ? B1 : B0;
  __bf16* xz  = dir ? xz1 : xz0;
  __bf16* res = dir ? res1 : res0;
  const int tid  = threadIdx.x;
  const int lane = tid & 63;
  const int wid  = tid >> 6;
  const int wm = wid & 1;
  const int wn = wid >> 1;
  const int mBase = blockIdx.x * BM;
  const int nBase = blockIdx.y * BN;
  const int lm = lane & 15;
  const int kq = (lane >> 4) * 8;

  __shared__ __bf16 As[BM*32];
  __shared__ __bf16 Bs[BN*32];

  const __bf16* aS[LA];
  const __bf16* bS[LB];
  {
    int colk = (tid & 3) * 8;
    #pragma unroll
    for (int ld=0; ld<LA; ld++){
      int r = mBase + ld*64 + (tid >> 2);
      if (dir==1){ int b = r >> 10, t = r & (L_-1); r = (b<<10) + (L_-1-t); }
      aS[ld] = A + (long)r*lda + colk;
    }
    #pragma unroll
    for (int ld=0; ld<LB; ld++){
      int r = nBase + ld*64 + (tid >> 2);
      bS[ld] = Bt + (long)r*ldb + colk;
    }
  }

  f32x4 acc[WMT][WNT] = {};
  for (int k0=0; k0<KK; k0+=32){
    #pragma unroll
    for (int ld=0; ld<LA; ld++)
      __builtin_amdgcn_global_load_lds(
        (const __attribute__((address_space(1))) void*)(aS[ld] + k0),
        (__attribute__((address_space(3))) void*)(&As[ld*2048 + tid*8]), 16, 0, 0);
    #pragma unroll
    for (int ld=0; ld<LB; ld++)
      __builtin_amdgcn_global_load_lds(
        (const __attribute__((address_space(1))) void*)(bS[ld] + k0),
        (__attribute__((address_space(3))) void*)(&Bs[ld*2048 + tid*8]), 16, 0, 0);
    __syncthreads();
    bf16x8 af[WMT], bfr[WNT];
    #pragma unroll
    for (int i=0;i<WMT;i++) af[i]  = *(const bf16x8*)&As[(wm*TM + i*16 + lm)*32 + kq];
    #pragma unroll
    for (int j=0;j<WNT;j++) bfr[j] = *(const bf16x8*)&Bs[(wn*TN + j*16 + lm)*32 + kq];
    #pragma unroll
    for (int i=0;i<WMT;i++)
      #pragma unroll
      for (int j=0;j<WNT;j++)
        acc[i][j] = __builtin_amdgcn_mfma_f32_16x16x32_bf16(af[i], bfr[j], acc[i][j], 0,0,0);
    __syncthreads();
  }

  #pragma unroll
  for (int i=0;i<WMT;i++){
    #pragma unroll
    for (int rr=0;rr<4;rr++){
      int r = mBase + wm*TM + i*16 + (lane>>4)*4 + rr;
      #pragma unroll
      for (int j=0;j<WNT;j++){
        int c = nBase + wn*TN + j*16 + lm;
        float v = acc[i][j][rr];
        if (c < DI) xz[(long)r*DI + c] = (__bf16)v;
        else        res[(long)r*DI + (c-DI)] = (__bf16)v;
      }
    }
  }
}

// ============ final fused GEMM ============
template<int BM,int BN,int KK>
__global__ __launch_bounds__(256) void gemm_fin_k(
    const __bf16* Af, const __bf16* Ab,
    const __bf16* Bt0, const __bf16* Bt1,
    void* Cout, const __bf16* bias, const void* resid)
{
  constexpr int TM = BM/2, TN = BN/2;
  constexpr int WMT = TM/16, WNT = TN/16;
  constexpr int LA = BM/64, LB = BN/64;

  const int of = flag_from_x(resid);
  const int tid  = threadIdx.x;
  const int lane = tid & 63;
  const int wid  = tid >> 6;
  const int wm = wid & 1;
  const int wn = wid >> 1;
  const int mBase = blockIdx.x * BM;
  const int nBase = blockIdx.y * BN;
  const int lm = lane & 15;
  const int kq = (lane >> 4) * 8;

  __shared__ __bf16 As[BM*32];
  __shared__ __bf16 Bs[BN*32];

  f32x4 acc[WMT][WNT] = {};
  #pragma unroll 1
  for (int dd=0; dd<2; dd++){
    const __bf16* A  = dd ? Ab  : Af;
    const __bf16* Bt = dd ? Bt1 : Bt0;
    const __bf16* aS[LA];
    const __bf16* bS[LB];
    {
      int colk = (tid & 3) * 8;
      #pragma unroll
      for (int ld=0; ld<LA; ld++){
        int r = mBase + ld*64 + (tid >> 2);
        if (dd==1){ int b = r >> 10, t = r & (L_-1); r = (b<<10) + (L_-1-t); }
        aS[ld] = A + (long)r*DI + colk;
      }
      #pragma unroll
      for (int ld=0; ld<LB; ld++){
        int r = nBase + ld*64 + (tid >> 2);
        bS[ld] = Bt + (long)r*DI + colk;
      }
    }
    for (int k0=0; k0<KK; k0+=32){
      #pragma unroll
      for (int ld=0; ld<LA; ld++)
        __builtin_amdgcn_global_load_lds(
          (const __attribute__((address_space(1))) void*)(aS[ld] + k0),
          (__attribute__((address_space(3))) void*)(&As[ld*2048 + tid*8]), 16, 0, 0);
      #pragma unroll
      for (int ld=0; ld<LB; ld++)
        __builtin_amdgcn_global_load_lds(
          (const __attribute__((address_space(1))) void*)(bS[ld] + k0),
          (__attribute__((address_space(3))) void*)(&Bs[ld*2048 + tid*8]), 16, 0, 0);
      __syncthreads();
      bf16x8 af[WMT], bfr[WNT];
      #pragma unroll
      for (int i=0;i<WMT;i++) af[i]  = *(const bf16x8*)&As[(wm*TM + i*16 + lm)*32 + kq];
      #pragma unroll
      for (int j=0;j<WNT;j++) bfr[j] = *(const bf16x8*)&Bs[(wn*TN + j*16 + lm)*32 + kq];
      #pragma unroll
      for (int i=0;i<WMT;i++)
        #pragma unroll
        for (int j=0;j<WNT;j++)
          acc[i][j] = __builtin_amdgcn_mfma_f32_16x16x32_bf16(af[i], bfr[j], acc[i][j], 0,0,0);
      __syncthreads();
    }
  }

  #pragma unroll
  for (int i=0;i<WMT;i++){
    #pragma unroll
    for (int rr=0;rr<4;rr++){
      int r = mBase + wm*TM + i*16 + (lane>>4)*4 + rr;
      #pragma unroll
      for (int j=0;j<WNT;j++){
        int c = nBase + wn*TN + j*16 + lm;
        float v = acc[i][j][rr];
        float rsd = of ? ((const float*)resid)[(long)r*DM + c]
                       : (float)((const __bf16*)resid)[(long)r*DM + c];
        v += (float)bias[c] + rsd;
        if (of) ((float*)Cout)[(long)r*DM + c] = v;
        else    ((__bf16*)Cout)[(long)r*DM + c] = (__bf16)v;
      }
    }
  }
}

// ============ scan phase A: conv + x-proj MFMA + local scan, with xs/sX write-through ============
__global__ __launch_bounds__(512) void scanA_k(
    const __bf16* xz0, const __bf16* xz1,
    const float* cw0, const float* cw1,
    const __bf16* cb0, const __bf16* cb1,
    const __bf16* xW0, const __bf16* xW1,
    const float* dw0, const float* dw1,
    const __bf16* dtB0, const __bf16* dtB1,
    const float* ALf0, const float* ALf1,
    __bf16* xg0, __bf16* xg1,
    float* sg0, float* sg1,
    float* hend, float* sumd)
{
  const int dir = blockIdx.z;
  const __bf16* xz  = dir ? xz1 : xz0;
  const float*  cw  = dir ? cw1 : cw0;
  const __bf16* cb  = dir ? cb1 : cb0;
  const __bf16* xWt = dir ? xW1 : xW0;
  const float*  dw  = dir ? dw1 : dw0;
  const __bf16* dtB = dir ? dtB1 : dtB0;
  const float*  ALf = dir ? ALf1 : ALf0;
  __bf16*       xg  = dir ? xg1 : xg0;
  float*        sg  = dir ? sg1 : sg0;

  const int b   = blockIdx.y;
  const int c   = blockIdx.x;
  const int tid = threadIdx.x;
  const int lane = tid & 63;
  const int wid  = tid >> 6;
  const int d   = tid;
  const int db  = dir*8 + b;
  const long row0 = (long)b*L_ + (long)c*CT;

  __shared__ __bf16 xs_s[CT*DI];    // 32KB, XOR-swizzled, row stride 1024B
  __shared__ float  sX[CT][48];     // dlt | B | C

  // ---- conv + silu -> xs LDS + global write-through (load-all-first) ----
  {
    const float q0 = cw[0*DI+d], q1 = cw[1*DI+d], q2 = cw[2*DI+d], q3 = cw[3*DI+d];
    const float cbv = (float)cb[d];
    int gt0 = c*CT;
    float xt[CT];
    #pragma unroll
    for (int t=0;t<CT;t++) xt[t] = (float)xz[(row0+t)*DI + d];
    float xm3 = (gt0-3 >= 0) ? (float)xz[(row0-3)*DI + d] : 0.f;
    float xm2 = (gt0-2 >= 0) ? (float)xz[(row0-2)*DI + d] : 0.f;
    float xm1 = (gt0-1 >= 0) ? (float)xz[(row0-1)*DI + d] : 0.f;
    #pragma unroll
    for (int t=0;t<CT;t++){
      float av = cbv;
      av += xm3*q0; av += xm2*q1; av += xm1*q2; av += xt[t]*q3;
      __bf16 sv = (__bf16)silu_f(av);
      *(__bf16*)((char*)xs_s + t*1024 + ((2*d) ^ ((t&7)<<4))) = sv;
      xg[(row0+t)*DI + d] = sv;
      xm3 = xm2; xm2 = xm1; xm1 = xt[t];
    }
  }
  __syncthreads();

  // ---- x-proj: sX[32][48] = xs[32][512] @ xW^T  (6 waves) + global write-through ----
  if (wid < 6){
    const int mb = (wid & 1) * 16;
    const int nb = (wid >> 1) * 16;
    const int lm = lane & 15;
    const int kq = (lane >> 4) * 8;
    const int row = mb + lm;
    const char* abase = (const char*)xs_s + row*1024;
    const int rsw = (row&7)<<4;
    const __bf16* Bt = xWt + (long)(nb + lm)*DI + kq;
    f32x4 acc = {};
    #pragma unroll
    for (int k0=0;k0<DI;k0+=32){
      bf16x8 af  = *(const bf16x8*)(abase + (((kq + k0)*2) ^ rsw));
      bf16x8 bfr = *(const bf16x8*)(Bt + k0);
      acc = __builtin_amdgcn_mfma_f32_16x16x32_bf16(af, bfr, acc, 0,0,0);
    }
    #pragma unroll
    for (int rr=0;rr<4;rr++){
      int r = mb + (lane>>4)*4 + rr;
      sX[r][nb + lm] = acc[rr];
      sg[(row0 + r)*48 + nb + lm] = acc[rr];
    }
  }

  // ---- per-thread scan state ----
  f32x2 dw2[8];
  { const f32x4* p = (const f32x4*)(dw + d*DTR);
    #pragma unroll
    for (int q=0;q<4;q++){ f32x4 v=p[q];
      dw2[q*2]   = f32x2{v[0],v[1]};
      dw2[q*2+1] = f32x2{v[2],v[3]}; } }
  float A[16];
  { const f32x4* p = (const f32x4*)(ALf + d*DS);
    #pragma unroll
    for (int q=0;q<4;q++){ f32x4 v=p[q];
      A[q*4]=-__expf(v[0]); A[q*4+1]=-__expf(v[1]); A[q*4+2]=-__expf(v[2]); A[q*4+3]=-__expf(v[3]); } }
  bool pow_ok = true;
  #pragma unroll
  for (int n=0;n<16;n++) pow_ok = pow_ok && (fabsf(A[n] + (float)(n+1)) < 0.003f*(n+1));
  const float dtbv = (float)dtB[d];

  f32x2 h2[8];
  #pragma unroll
  for (int i=0;i<8;i++) h2[i] = f32x2{0.f,0.f};
  float sdelta = 0.f;
  __syncthreads();

  if (pow_ok){
    #pragma unroll 2
    for (int t=0;t<CT;t++){
      f32x2 z2 = f32x2{dtbv, 0.f};
      #pragma unroll
      for (int i=0;i<8;i++){
        f32x2 qv = *(const f32x2*)&sX[t][i*2];
        z2 += qv*dw2[i];
      }
      float delta = softplus_f(z2[0]+z2[1]);
      sdelta += delta;
      float xv = (float)*(const __bf16*)((const char*)xs_s + t*1024 + ((2*d) ^ ((t&7)<<4)));
      float dx = delta*xv;
      f32x2 dx2 = f32x2{dx, dx};
      float e1 = __expf(-delta), e2v = e1*e1;
      f32x2 e22 = f32x2{e2v, e2v};
      f32x2 pw = f32x2{e1, e2v};
      #pragma unroll
      for (int i=0;i<8;i++){
        f32x2 Bv = *(const f32x2*)&sX[t][16+i*2];
        h2[i] = pw*h2[i] + dx2*Bv;
        pw = pw*e22;
      }
    }
  } else {
    #pragma unroll 2
    for (int t=0;t<CT;t++){
      f32x2 z2 = f32x2{dtbv, 0.f};
      #pragma unroll
      for (int i=0;i<8;i++){
        f32x2 qv = *(const f32x2*)&sX[t][i*2];
        z2 += qv*dw2[i];
      }
      float delta = softplus_f(z2[0]+z2[1]);
      sdelta += delta;
      float xv = (float)*(const __bf16*)((const char*)xs_s + t*1024 + ((2*d) ^ ((t&7)<<4)));
      float dx = delta*xv;
      #pragma unroll
      for (int i=0;i<8;i++){
        f32x2 Bv = *(const f32x2*)&sX[t][16+i*2];
        f32x2 pw = f32x2{__expf(delta*A[i*2]), __expf(delta*A[i*2+1])};
        h2[i] = pw*h2[i] + f32x2{dx,dx}*Bv;
      }
    }
  }

  long hb = (((long)db*NC + c)*DI + d)*16;
  f32x4* hp = (f32x4*)(hend + hb);
  #pragma unroll
  for (int q=0;q<4;q++){
    f32x4 v; v[0]=h2[q*2][0]; v[1]=h2[q*2][1]; v[2]=h2[q*2+1][0]; v[3]=h2[q*2+1][1];
    hp[q]=v;
  }
  sumd[((long)db*NC + c)*DI + d] = sdelta;
}

// ============ phase B: cross-chunk scan, register-prefetched ============
__global__ __launch_bounds__(256) void scanB_k(
    const float* ALf0, const float* ALf1,
    const float* hend, const float* sumd, float* Hbuf)
{
  int gid = blockIdx.x*256 + threadIdx.x;
  int n  = gid & 15;
  int d  = (gid>>4) & 511;
  int db = gid >> 13;
  const float* ALf = (db>=8) ? ALf1 : ALf0;
  float A_dn = -__expf(ALf[d*DS + n]);
  const long base0 = (((long)db*NC)*DI + d)*16 + n;
  const long cstr  = (long)DI*16;
  const long sbase = (long)db*NC*DI + d;
  float H = 0.f;
  #pragma unroll 1
  for (int g=0; g<NC/16; g++){
    float he[16], Sv[16];
    #pragma unroll
    for (int k=0;k<16;k++){
      he[k] = hend[base0 + (long)(g*16+k)*cstr];
      Sv[k] = sumd[sbase + (long)(g*16+k)*DI];
    }
    #pragma unroll
    for (int k=0;k<16;k++){
      Hbuf[base0 + (long)(g*16+k)*cstr] = H;
      H = he[k] + __expf(A_dn*Sv[k])*H;
    }
  }
}

// ============ scan phase C: re-scan + gate only (xs/sX precomputed), d-split ============
__global__ __launch_bounds__(256, 4) void scanC_k(
    const __bf16* __restrict__ xg0, const __bf16* __restrict__ xg1,
    const float* __restrict__ sg0, const float* __restrict__ sg1,
    __bf16* __restrict__ res0, __bf16* __restrict__ res1,
    const float* __restrict__ dw0, const float* __restrict__ dw1,
    const __bf16* __restrict__ dtB0, const __bf16* __restrict__ dtB1,
    const float* __restrict__ ALf0, const float* __restrict__ ALf1,
    const __bf16* __restrict__ Dp0, const __bf16* __restrict__ Dp1,
    const float* __restrict__ Hbuf)
{
  const int zc  = blockIdx.z;       // 0..3 = dir*2 + dgroup
  const int dir = zc >> 1;
  const int dg  = zc & 1;
  const __bf16* xg  = dir ? xg1 : xg0;
  const float*  sg  = dir ? sg1 : sg0;
  __bf16*       res = dir ? res1 : res0;
  const float*  dw  = dir ? dw1 : dw0;
  const __bf16* dtB = dir ? dtB1 : dtB0;
  const float*  ALf = dir ? ALf1 : ALf0;
  const __bf16* Dp  = dir ? Dp1 : Dp0;

  const int b   = blockIdx.y;
  const int c   = blockIdx.x;       // 0..NC-1
  const int dl  = threadIdx.x;      // 0..255
  const int d   = dg*256 + dl;
  const int db  = dir*8 + b;
  const long row0 = (long)b*L_ + (long)c*CT;

  __shared__ __bf16 xs_l[CT*256];   // [32][256] bf16, row stride 512B (16KB)
  __shared__ float  sX[CT][48];     // dlt | B | C (6KB)

  // stage this block's xs sub-tile (cols dg*256..+256) via global_load_lds
  {
    const __bf16* src = xg + row0*DI + dg*256;
    #pragma unroll
    for (int i=0;i<4;i++){
      int r = i*8 + (dl>>5);
      int cs = (dl&31)*8;
      __builtin_amdgcn_global_load_lds(
        (const __attribute__((address_space(1))) void*)(src + (long)r*DI + cs),
        (__attribute__((address_space(3))) void*)(&xs_l[i*2048 + dl*8]), 16, 0, 0);
    }
  }
  // stage sX rows
  for (int v=dl; v<CT*12; v+=256)
    ((f32x4*)sX)[v] = ((const f32x4*)(sg + row0*48))[v];

  f32x2 dw2[8];
  { const f32x4* p = (const f32x4*)(dw + d*DTR);
    #pragma unroll
    for (int q=0;q<4;q++){ f32x4 v=p[q];
      dw2[q*2]   = f32x2{v[0],v[1]};
      dw2[q*2+1] = f32x2{v[2],v[3]}; } }
  float A[16];
  { const f32x4* p = (const f32x4*)(ALf + d*DS);
    #pragma unroll
    for (int q=0;q<4;q++){ f32x4 v=p[q];
      A[q*4]=-__expf(v[0]); A[q*4+1]=-__expf(v[1]); A[q*4+2]=-__expf(v[2]); A[q*4+3]=-__expf(v[3]); } }
  bool pow_ok = true;
  #pragma unroll
  for (int n=0;n<16;n++) pow_ok = pow_ok && (fabsf(A[n] + (float)(n+1)) < 0.003f*(n+1));
  const float dtbv = (float)dtB[d];
  const float Dpv  = (float)Dp[d];

  f32x2 h2[8];
  { long hb = (((long)db*NC + c)*DI + d)*16;
    const f32x4* p = (const f32x4*)(Hbuf + hb);
    #pragma unroll
    for (int q=0;q<4;q++){ f32x4 v = p[q];
      h2[q*2]   = f32x2{v[0],v[1]};
      h2[q*2+1] = f32x2{v[2],v[3]}; } }
  __syncthreads();

  if (pow_ok){
    #pragma unroll 2
    for (int t=0;t<CT;t++){
      long row = row0 + t;
      f32x2 z2 = f32x2{dtbv, 0.f};
      #pragma unroll
      for (int i=0;i<8;i++){
        f32x2 qv = *(const f32x2*)&sX[t][i*2];
        z2 += qv*dw2[i];
      }
      float delta = softplus_f(z2[0]+z2[1]);
      float xv = (float)xs_l[t*256 + dl];
      float dx = delta*xv;
      f32x2 dx2 = f32x2{dx, dx};
      float e1 = __expf(-delta), e2v = e1*e1;
      f32x2 e22 = f32x2{e2v, e2v};
      f32x2 pw = f32x2{e1, e2v};
      f32x2 p2 = f32x2{0.f, 0.f};
      #pragma unroll
      for (int i=0;i<8;i++){
        f32x2 Bv = *(const f32x2*)&sX[t][16+i*2];
        f32x2 Cv = *(const f32x2*)&sX[t][32+i*2];
        h2[i] = pw*h2[i] + dx2*Bv;
        p2 += h2[i]*Cv;
        pw = pw*e22;
      }
      float yv = p2[0] + p2[1] + Dpv*xv;
      float rv = (float)res[row*DI + d];
      res[row*DI + d] = (__bf16)(yv * silu_f(rv));
    }
  } else {
    #pragma unroll 2
    for (int t=0;t<CT;t++){
      long row = row0 + t;
      f32x2 z2 = f32x2{dtbv, 0.f};
      #pragma unroll
      for (int i=0;i<8;i++){
        f32x2 qv = *(const f32x2*)&sX[t][i*2];
        z2 += qv*dw2[i];
      }
      float delta = softplus_f(z2[0]+z2[1]);
      float xv = (float)xs_l[t*256 + dl];
      float dx = delta*xv;
      f32x2 p2 = f32x2{0.f, 0.f};
      #pragma unroll
      for (int i=0;i<8;i++){
        f32x2 Bv = *(const f32x2*)&sX[t][16+i*2];
        f32x2 Cv = *(const f32x2*)&sX[t][32+i*2];
        f32x2 pw = f32x2{__expf(delta*A[i*2]), __expf(delta*A[i*2+1])};
        h2[i] = pw*h2[i] + f32x2{dx,dx}*Bv;
        p2 += h2[i]*Cv;
      }
      float yv = p2[0] + p2[1] + Dpv*xv;
      float rv = (float)res[row*DI + d];
      res[row*DI + d] = (__bf16)(yv * silu_f(rv));
    }
  }
}

// ---------------- launch ----------------
extern "C" void kernel_launch(void* const* d_in, const int* in_sizes, int n_in,
                              void* d_out, int out_size, void* d_ws, size_t ws_size,
                              hipStream_t stream)
{
  const size_t MB = 1u<<20;
  if (ws_size < 160*MB) return;

  char* w = (char*)d_ws;
  __bf16* xz[2]   = {(__bf16*)(w + 0),      (__bf16*)(w + 8*MB)};
  __bf16* res[2]  = {(__bf16*)(w + 16*MB),  (__bf16*)(w + 24*MB)};
  __bf16* xs_g[2] = {(__bf16*)(w + 32*MB),  (__bf16*)(w + 40*MB)};
  __bf16* xn      = (__bf16*)(w + 48*MB);

  char* wp = w + 52*MB;
  auto carve = [&](size_t bytes)->void*{
    void* p = wp;
    wp += (bytes + 255) & ~(size_t)255;
    return p;
  };
  __bf16 *inWt[2], *xWt[2], *outWr[2], *BtC[2];
  float *dtWt[2], *convWt[2];
  for (int m=0;m<2;m++){
    inWt[m]   = (__bf16*)carve((size_t)(2*DI)*DM*2);
    xWt[m]    = (__bf16*)carve((size_t)48*DI*2);
    outWr[m]  = (__bf16*)carve((size_t)DI*DM*2);
    BtC[m]    = (__bf16*)carve((size_t)DM*DI*2);
    dtWt[m]   = (float*)carve((size_t)DI*DTR*4);
    convWt[m] = (float*)carve((size_t)4*DI*4);
  }
  __bf16* fusWt = (__bf16*)carve((size_t)DM*(2*DM)*2);
  float* ALf[2] = {(float*)carve((size_t)DI*DS*4), (float*)carve((size_t)DI*DS*4)};

  char* cp = w + 57*MB;
  auto carve2 = [&](size_t elems)->__bf16*{
    __bf16* p = (__bf16*)cp;
    cp += (elems*2 + 255) & ~(size_t)255;
    return p;
  };
  __bf16* ngc = carve2(DM);
  __bf16* nbc = carve2(DM);
  __bf16 *convBc[2], *dtBc[2], *Dpc[2];
  for (int m=0;m<2;m++){
    convBc[m] = carve2(DI);
    dtBc[m]   = carve2(DI);
    Dpc[m]    = carve2(DI);
  }
  __bf16* fusBc = carve2(DM);

  float* sXg[2] = {(float*)(w + 58*MB), (float*)(w + 60*MB)};  // 1.57MB each
  float* hend = (float*)(w + 90*MB);   // 16.8MB
  float* Hbuf = (float*)(w + 110*MB);  // 16.8MB
  float* sumd = (float*)(w + 130*MB);  // 1MB

  // elementwise prep jobs
  PrepArgs pa;
  int ji = 0;
  size_t tot = 0;
  auto addj = [&](const void* s, void* dst, int rows, int cols, int f32o){
    pa.j[ji++] = {s, dst, rows, cols, f32o};
    tot += (size_t)rows*cols;
  };
  for (int m=0;m<2;m++){
    int base = 3 + m*9;
    addj(d_in[base+3], xWt[m],   DI,  48,   0);
    addj(d_in[base+8], outWr[m], 1,   DI*DM,0);
    addj(d_in[base+4], dtWt[m],  DTR, DI,   1);
    addj(d_in[base+1], convWt[m],DI,  4,    1);
    addj(d_in[base+2], convBc[m],1, DI, 0);
    addj(d_in[base+5], dtBc[m],  1, DI, 0);
    addj(d_in[base+6], (void*)ALf[m], 1, DI*DS, 1);
    addj(d_in[base+7], Dpc[m],   1, DI, 0);
  }
  addj(d_in[1],  ngc, 1, DM, 0);
  addj(d_in[2],  nbc, 1, DM, 0);
  addj(d_in[22], fusBc, 1, DM, 0);
  pa.nj = ji;

  // tiled transpose jobs
  TArgs ta;
  ta.j[0] = { d_in[3],  inWt[0], DM,   2*DI }; ta.ntiles[0] = (DM/64)*((2*DI)/64);
  ta.j[1] = { d_in[12], inWt[1], DM,   2*DI }; ta.ntiles[1] = (DM/64)*((2*DI)/64);
  ta.j[2] = { d_in[21], fusWt,   2*DM, DM   }; ta.ntiles[2] = ((2*DM)/64)*(DM/64);
  ta.nj = 3;
  ta.ntot = ta.ntiles[0]+ta.ntiles[1]+ta.ntiles[2];
  int prepBlocks = (int)((tot+255)/256);
  wprep_k<<<ta.ntot + prepBlocks, 256, 0, stream>>>(ta, pa, d_in[0]);

  lnw_k<<<M_/4 + 64, 256, 0, stream>>>(
      d_in[0], ngc, nbc, xn, fusWt, outWr[0], outWr[1], BtC[0], BtC[1]);

  gemm_in_k<128,128,256><<<dim3(M_/128, (2*DI)/128, 2), 256, 0, stream>>>(
      xn, inWt[0], inWt[1], xz[0], xz[1], res[0], res[1], DM, DM);

  scanA_k<<<dim3(NC, B_, 2), 512, 0, stream>>>(
      xz[0], xz[1], convWt[0], convWt[1], convBc[0], convBc[1],
      xWt[0], xWt[1], dtWt[0], dtWt[1],
      dtBc[0], dtBc[1], ALf[0], ALf[1],
      xs_g[0], xs_g[1], sXg[0], sXg[1],
      hend, sumd);
  scanB_k<<<131072/256, 256, 0, stream>>>(ALf[0], ALf[1], hend, sumd, Hbuf);
  scanC_k<<<dim3(NC, B_, 4), 256, 0, stream>>>(
      xs_g[0], xs_g[1], sXg[0], sXg[1], res[0], res[1],
      dtWt[0], dtWt[1], dtBc[0], dtBc[1], ALf[0], ALf[1], Dpc[0], Dpc[1], Hbuf);

  gemm_fin_k<64,64,DI><<<dim3(M_/64, DM/64, 1), 256, 0, stream>>>(
      res[0], res[1], BtC[0], BtC[1], d_out, fusBc, d_in[0]);
}